// Round 1
// baseline (2660.335 us; speedup 1.0000x reference)
//
#include <hip/hip_runtime.h>
#include <cstdint>
#include <cstddef>

// ---------------- constants ----------------
#define BATCH 32
#define LSEQ  256
#define DMODEL 384
#define DINNER 768
#define NSTATE 16
#define RLOW   48
#define KCONV  4
#define NCLS   1000
#define NLAYER 4
#define KPATCH 588   // 3*14*14
#define NROWS  (BATCH*LSEQ)   // 8192

__device__ __forceinline__ float sigmoidf_(float x) { return 1.f / (1.f + __expf(-x)); }
__device__ __forceinline__ float siluf_(float x)    { return x / (1.f + __expf(-x)); }
__device__ __forceinline__ float softplusf_(float x){ return fmaxf(x, 0.f) + log1pf(__expf(-fabsf(x))); }

// ---------------- im2col for patch embed ----------------
// col[(b*256+l)][c*196 + i*14 + j] = x[b][c][py*14+i][px*14+j],  l = py*16+px
__global__ void im2col_patch(const float* __restrict__ x, float* __restrict__ col, int total) {
    int idx = blockIdx.x * 256 + threadIdx.x;
    if (idx >= total) return;
    int c588 = idx % KPATCH;
    int row  = idx / KPATCH;
    int b = row >> 8, l = row & 255;
    int py = l >> 4, px = l & 15;
    int c = c588 / 196;
    int rem = c588 % 196;
    int i = rem / 14, j = rem % 14;
    col[idx] = x[(((size_t)(b * 3 + c) * 224) + py * 14 + i) * 224 + px * 14 + j];
}

// ---------------- generic tiled GEMM: C[M,N] = A[M,K] * W[N,K]^T ----------------
// EPI: 0 = none, 1 = +bias, 2 = softplus(+bias), 3 = +resid
template <int EPI>
__global__ __launch_bounds__(256) void gemm_tn(
    const float* __restrict__ A, int lda,
    const float* __restrict__ W, int ldw,
    float* __restrict__ C, int ldc,
    int M, int N, int K,
    const float* __restrict__ bias,
    const float* __restrict__ resid)
{
    __shared__ __align__(16) float As[16][68];
    __shared__ __align__(16) float Ws[16][68];
    const int t  = threadIdx.x;
    const int bm = blockIdx.y * 64, bn = blockIdx.x * 64;
    const int tx = t & 15, ty = t >> 4;
    const int lr = t >> 2;          // 0..63 tile row/col for staging
    const int lk = (t & 3) << 2;    // 0,4,8,12 k-offset for staging

    float acc[4][4] = {};

    for (int k0 = 0; k0 < K; k0 += 16) {
        float4 va = {0.f, 0.f, 0.f, 0.f};
        {
            int row = bm + lr, kb = k0 + lk;
            if (row < M && kb < K) {
                const float* p = A + (size_t)row * lda + kb;
                if (kb + 3 < K) va = *(const float4*)p;
                else {
                    va.x = p[0];
                    if (kb + 1 < K) va.y = p[1];
                    if (kb + 2 < K) va.z = p[2];
                }
            }
        }
        float4 vw = {0.f, 0.f, 0.f, 0.f};
        {
            int col = bn + lr, kb = k0 + lk;
            if (col < N && kb < K) {
                const float* p = W + (size_t)col * ldw + kb;
                if (kb + 3 < K) vw = *(const float4*)p;
                else {
                    vw.x = p[0];
                    if (kb + 1 < K) vw.y = p[1];
                    if (kb + 2 < K) vw.z = p[2];
                }
            }
        }
        __syncthreads();
        As[lk + 0][lr] = va.x; As[lk + 1][lr] = va.y; As[lk + 2][lr] = va.z; As[lk + 3][lr] = va.w;
        Ws[lk + 0][lr] = vw.x; Ws[lk + 1][lr] = vw.y; Ws[lk + 2][lr] = vw.z; Ws[lk + 3][lr] = vw.w;
        __syncthreads();

#pragma unroll
        for (int kk = 0; kk < 16; ++kk) {
            float4 av = *(const float4*)&As[kk][ty << 2];
            float4 wv = *(const float4*)&Ws[kk][tx << 2];
            float a4[4] = {av.x, av.y, av.z, av.w};
            float w4[4] = {wv.x, wv.y, wv.z, wv.w};
#pragma unroll
            for (int i = 0; i < 4; ++i)
#pragma unroll
                for (int j = 0; j < 4; ++j)
                    acc[i][j] += a4[i] * w4[j];
        }
    }

#pragma unroll
    for (int i = 0; i < 4; ++i) {
        int r = bm + (ty << 2) + i;
        if (r >= M) continue;
#pragma unroll
        for (int j = 0; j < 4; ++j) {
            int c = bn + (tx << 2) + j;
            if (c >= N) continue;
            float v = acc[i][j];
            if (EPI == 1 || EPI == 2) v += bias[c];
            if (EPI == 2) v = softplusf_(v);
            if (EPI == 3) v += resid[(size_t)r * ldc + c];
            C[(size_t)r * ldc + c] = v;
        }
    }
}

// ---------------- layernorm over last dim (=384), wave per row ----------------
__global__ __launch_bounds__(256) void ln_rows(
    const float* __restrict__ x, const float* __restrict__ w,
    const float* __restrict__ b, float* __restrict__ out, int rows)
{
    int wave = threadIdx.x >> 6, lane = threadIdx.x & 63;
    int row = blockIdx.x * 4 + wave;
    if (row >= rows) return;
    const float* xr = x + (size_t)row * DMODEL;
    float v[6];
    float s = 0.f, ss = 0.f;
#pragma unroll
    for (int j = 0; j < 6; ++j) {
        v[j] = xr[lane + 64 * j];
        s += v[j];
        ss += v[j] * v[j];
    }
#pragma unroll
    for (int m = 1; m < 64; m <<= 1) {
        s  += __shfl_xor(s, m);
        ss += __shfl_xor(ss, m);
    }
    float mean = s * (1.f / DMODEL);
    float var  = ss * (1.f / DMODEL) - mean * mean;
    float rstd = rsqrtf(var + 1e-5f);
    float* orow = out + (size_t)row * DMODEL;
#pragma unroll
    for (int j = 0; j < 6; ++j) {
        int c = lane + 64 * j;
        orow[c] = (v[j] - mean) * rstd * w[c] + b[c];
    }
}

// ---------------- causal depthwise conv1d (K=4) + bias + SiLU ----------------
// in: xb part of xz (B,L,1536) cols [0,768);  out: (B,L,768)
__global__ void dwconv_silu(const float* __restrict__ xz, const float* __restrict__ cw,
                            const float* __restrict__ cb, float* __restrict__ out, int total)
{
    int idx = blockIdx.x * 256 + threadIdx.x;
    if (idx >= total) return;
    int d = idx % DINNER;
    int l = (idx / DINNER) & 255;
    int b = idx / (DINNER * 256);
    const float* src = xz + (size_t)(b * 256) * 1536 + d;
    const float* wv = cw + d * 4;
    float acc = cb[d];
#pragma unroll
    for (int k = 0; k < 4; ++k) {
        int ls = l - 3 + k;
        if (ls >= 0) acc += src[(size_t)ls * 1536] * wv[k];
    }
    out[idx] = siluf_(acc);
}

// ---------------- selective SSM scan: thread per (b,d), 16 states in regs ----------------
__global__ __launch_bounds__(256) void ssm_scan(
    const float* __restrict__ dt, const float* __restrict__ xb,
    const float* __restrict__ proj, const float* __restrict__ A_log,
    const float* __restrict__ Dvec, float* __restrict__ y)
{
    int b = blockIdx.y;
    int d = blockIdx.x * 256 + threadIdx.x;
    int tid = threadIdx.x;
    __shared__ float sB[NSTATE], sC[NSTATE];
    float a[NSTATE], h[NSTATE];
#pragma unroll
    for (int n = 0; n < NSTATE; ++n) {
        a[n] = -__expf(A_log[(size_t)d * NSTATE + n]);
        h[n] = 0.f;
    }
    float Dv = Dvec[d];
    for (int l = 0; l < LSEQ; ++l) {
        __syncthreads();
        if (tid < 32) {
            float v = proj[(size_t)(b * LSEQ + l) * 80 + RLOW + tid];
            if (tid < 16) sB[tid] = v; else sC[tid - 16] = v;
        }
        __syncthreads();
        size_t off = (size_t)(b * LSEQ + l) * DINNER + d;
        float dtv = dt[off], xv = xb[off];
        float dtx = dtv * xv;
        float yv = 0.f;
#pragma unroll
        for (int n = 0; n < NSTATE; ++n) {
            h[n] = h[n] * __expf(dtv * a[n]) + dtx * sB[n];
            yv += h[n] * sC[n];
        }
        y[off] = yv + xv * Dv;
    }
}

// ---------------- gating: y *= silu(z) ----------------
__global__ void gate_silu(float* __restrict__ y, const float* __restrict__ xz, int total)
{
    int idx = blockIdx.x * 256 + threadIdx.x;
    if (idx >= total) return;
    int d = idx % DINNER;
    int row = idx / DINNER;
    float z = xz[(size_t)row * 1536 + DINNER + d];
    y[idx] = y[idx] * siluf_(z);
}

// ---------------- mean pool over L ----------------
__global__ void mean_pool(const float* __restrict__ x, float* __restrict__ out)
{
    int idx = blockIdx.x * 256 + threadIdx.x;
    if (idx >= BATCH * DMODEL) return;
    int b = idx / DMODEL, m = idx % DMODEL;
    const float* p = x + (size_t)(b * LSEQ) * DMODEL + m;
    float s = 0.f;
    for (int l = 0; l < LSEQ; ++l) s += p[(size_t)l * DMODEL];
    out[idx] = s * (1.f / LSEQ);
}

// ---------------- host launch ----------------
static inline int ceil_div(int a, int b) { return (a + b - 1) / b; }

extern "C" void kernel_launch(void* const* d_in, const int* in_sizes, int n_in,
                              void* d_out, int out_size, void* d_ws, size_t ws_size,
                              hipStream_t stream)
{
    const float* x        = (const float*)d_in[0];
    const float* patch_w  = (const float*)d_in[1];
    const float* patch_b  = (const float*)d_in[2];
    const float* norm_w   = (const float*)d_in[3];
    const float* norm_b   = (const float*)d_in[4];
    const float* in_proj  = (const float*)d_in[5];
    const float* conv_w   = (const float*)d_in[6];
    const float* conv_b   = (const float*)d_in[7];
    const float* A_log    = (const float*)d_in[8];
    const float* D_ssm    = (const float*)d_in[9];
    const float* xproj_w  = (const float*)d_in[10];
    const float* dtproj_w = (const float*)d_in[11];
    const float* dtproj_b = (const float*)d_in[12];
    const float* out_proj = (const float*)d_in[13];
    const float* fnorm_w  = (const float*)d_in[14];
    const float* fnorm_b  = (const float*)d_in[15];
    const float* cls_w    = (const float*)d_in[16];
    const float* cls_b    = (const float*)d_in[17];
    float* out = (float*)d_out;

    float* ws = (float*)d_ws;
    // workspace layout (floats); im2col shares the xz region (disjoint liveness)
    const size_t OFF_XZ   = 0;                       // 8192*1536 = 12,582,912 (im2col: 8192*588 fits)
    const size_t OFF_T    = OFF_XZ + (size_t)NROWS * 1536;
    const size_t OFF_XN   = OFF_T + (size_t)NROWS * DMODEL;
    const size_t OFF_XB   = OFF_XN + (size_t)NROWS * DMODEL;
    const size_t OFF_PROJ = OFF_XB + (size_t)NROWS * DINNER;
    const size_t OFF_DT   = OFF_PROJ + (size_t)NROWS * 80;
    const size_t OFF_POOL = OFF_DT + (size_t)NROWS * DINNER;

    float* col    = ws + OFF_XZ;
    float* t      = ws + OFF_T;
    float* xn     = ws + OFF_XN;
    float* xz     = ws + OFF_XZ;
    float* xb     = ws + OFF_XB;
    float* proj   = ws + OFF_PROJ;
    float* dtbuf  = ws + OFF_DT;
    float* pooled = ws + OFF_POOL;

    // 1. im2col + patch-embed GEMM  -> t (8192, 384)
    {
        int total = NROWS * KPATCH;
        im2col_patch<<<ceil_div(total, 256), 256, 0, stream>>>(x, col, total);
        dim3 g(ceil_div(DMODEL, 64), ceil_div(NROWS, 64));
        gemm_tn<1><<<g, 256, 0, stream>>>(col, KPATCH, patch_w, KPATCH, t, DMODEL,
                                          NROWS, DMODEL, KPATCH, patch_b, nullptr);
    }

    // 2. mamba blocks
    for (int l = 0; l < NLAYER; ++l) {
        const float* nw  = norm_w   + (size_t)l * DMODEL;
        const float* nb  = norm_b   + (size_t)l * DMODEL;
        const float* ipw = in_proj  + (size_t)l * 2 * DINNER * DMODEL;
        const float* cw  = conv_w   + (size_t)l * DINNER * KCONV;
        const float* cb  = conv_b   + (size_t)l * DINNER;
        const float* al  = A_log    + (size_t)l * DINNER * NSTATE;
        const float* dp  = D_ssm    + (size_t)l * DINNER;
        const float* xw  = xproj_w  + (size_t)l * 80 * DINNER;
        const float* dtw = dtproj_w + (size_t)l * DINNER * RLOW;
        const float* dtb = dtproj_b + (size_t)l * DINNER;
        const float* opw = out_proj + (size_t)l * DMODEL * DINNER;

        // LN
        ln_rows<<<NROWS / 4, 256, 0, stream>>>(t, nw, nb, xn, NROWS);
        // in_proj: (8192,384)@(1536,384)^T -> xz (8192,1536)
        {
            dim3 g(ceil_div(2 * DINNER, 64), ceil_div(NROWS, 64));
            gemm_tn<0><<<g, 256, 0, stream>>>(xn, DMODEL, ipw, DMODEL, xz, 2 * DINNER,
                                              NROWS, 2 * DINNER, DMODEL, nullptr, nullptr);
        }
        // causal depthwise conv + silu -> xb (8192,768)
        {
            int total = NROWS * DINNER;
            dwconv_silu<<<ceil_div(total, 256), 256, 0, stream>>>(xz, cw, cb, xb, total);
        }
        // xproj: (8192,768)@(80,768)^T -> proj (8192,80)
        {
            dim3 g(ceil_div(80, 64), ceil_div(NROWS, 64));
            gemm_tn<0><<<g, 256, 0, stream>>>(xb, DINNER, xw, DINNER, proj, 80,
                                              NROWS, 80, DINNER, nullptr, nullptr);
        }
        // dtproj + softplus: (8192,48)@(768,48)^T -> dtbuf (8192,768)
        {
            dim3 g(ceil_div(DINNER, 64), ceil_div(NROWS, 64));
            gemm_tn<2><<<g, 256, 0, stream>>>(proj, 80, dtw, RLOW, dtbuf, DINNER,
                                              NROWS, DINNER, RLOW, dtb, nullptr);
        }
        // scan (y written in-place over dtbuf)
        {
            dim3 g(DINNER / 256, BATCH);
            ssm_scan<<<g, 256, 0, stream>>>(dtbuf, xb, proj, al, dp, dtbuf);
        }
        // gate
        {
            int total = NROWS * DINNER;
            gate_silu<<<ceil_div(total, 256), 256, 0, stream>>>(dtbuf, xz, total);
        }
        // out_proj + residual: (8192,768)@(384,768)^T + t -> t
        {
            dim3 g(ceil_div(DMODEL, 64), ceil_div(NROWS, 64));
            gemm_tn<3><<<g, 256, 0, stream>>>(dtbuf, DINNER, opw, DINNER, t, DMODEL,
                                              NROWS, DMODEL, DINNER, nullptr, t);
        }
    }

    // 3. final LN -> xn, mean pool -> pooled, classifier -> out
    ln_rows<<<NROWS / 4, 256, 0, stream>>>(t, fnorm_w, fnorm_b, xn, NROWS);
    mean_pool<<<ceil_div(BATCH * DMODEL, 256), 256, 0, stream>>>(xn, pooled);
    {
        dim3 g(ceil_div(NCLS, 64), ceil_div(BATCH, 64));
        gemm_tn<1><<<g, 256, 0, stream>>>(pooled, DMODEL, cls_w, DMODEL, out, NCLS,
                                          BATCH, NCLS, DMODEL, cls_b, nullptr);
    }
}

// Round 2
// 1846.558 us; speedup vs baseline: 1.4407x; 1.4407x over previous
//
#include <hip/hip_runtime.h>
#include <cstdint>
#include <cstddef>

// ---------------- constants ----------------
#define BATCH 32
#define LSEQ  256
#define DMODEL 384
#define DINNER 768
#define NSTATE 16
#define RLOW   48
#define KCONV  4
#define NCLS   1000
#define NLAYER 4
#define KPATCH 588   // 3*14*14
#define NROWS  (BATCH*LSEQ)   // 8192
#define CCH 16   // number of chunks over L
#define LCH 16   // chunk length (CCH*LCH == LSEQ)

__device__ __forceinline__ float sigmoidf_(float x) { return 1.f / (1.f + __expf(-x)); }
__device__ __forceinline__ float siluf_(float x)    { return x / (1.f + __expf(-x)); }
__device__ __forceinline__ float softplusf_(float x){ return fmaxf(x, 0.f) + log1pf(__expf(-fabsf(x))); }

// ---------------- im2col for patch embed ----------------
__global__ void im2col_patch(const float* __restrict__ x, float* __restrict__ col, int total) {
    int idx = blockIdx.x * 256 + threadIdx.x;
    if (idx >= total) return;
    int c588 = idx % KPATCH;
    int row  = idx / KPATCH;
    int b = row >> 8, l = row & 255;
    int py = l >> 4, px = l & 15;
    int c = c588 / 196;
    int rem = c588 % 196;
    int i = rem / 14, j = rem % 14;
    col[idx] = x[(((size_t)(b * 3 + c) * 224) + py * 14 + i) * 224 + px * 14 + j];
}

// ---------------- generic tiled GEMM: C[M,N] = A[M,K] * W[N,K]^T ----------------
// EPI: 0 = none, 1 = +bias, 2 = softplus(+bias), 3 = +resid
template <int EPI>
__global__ __launch_bounds__(256) void gemm_tn(
    const float* __restrict__ A, int lda,
    const float* __restrict__ W, int ldw,
    float* __restrict__ C, int ldc,
    int M, int N, int K,
    const float* __restrict__ bias,
    const float* __restrict__ resid)
{
    __shared__ __align__(16) float As[16][68];
    __shared__ __align__(16) float Ws[16][68];
    const int t  = threadIdx.x;
    const int bm = blockIdx.y * 64, bn = blockIdx.x * 64;
    const int tx = t & 15, ty = t >> 4;
    const int lr = t >> 2;
    const int lk = (t & 3) << 2;

    float acc[4][4] = {};

    for (int k0 = 0; k0 < K; k0 += 16) {
        float4 va = {0.f, 0.f, 0.f, 0.f};
        {
            int row = bm + lr, kb = k0 + lk;
            if (row < M && kb < K) {
                const float* p = A + (size_t)row * lda + kb;
                if (kb + 3 < K) va = *(const float4*)p;
                else {
                    va.x = p[0];
                    if (kb + 1 < K) va.y = p[1];
                    if (kb + 2 < K) va.z = p[2];
                }
            }
        }
        float4 vw = {0.f, 0.f, 0.f, 0.f};
        {
            int col = bn + lr, kb = k0 + lk;
            if (col < N && kb < K) {
                const float* p = W + (size_t)col * ldw + kb;
                if (kb + 3 < K) vw = *(const float4*)p;
                else {
                    vw.x = p[0];
                    if (kb + 1 < K) vw.y = p[1];
                    if (kb + 2 < K) vw.z = p[2];
                }
            }
        }
        __syncthreads();
        As[lk + 0][lr] = va.x; As[lk + 1][lr] = va.y; As[lk + 2][lr] = va.z; As[lk + 3][lr] = va.w;
        Ws[lk + 0][lr] = vw.x; Ws[lk + 1][lr] = vw.y; Ws[lk + 2][lr] = vw.z; Ws[lk + 3][lr] = vw.w;
        __syncthreads();

#pragma unroll
        for (int kk = 0; kk < 16; ++kk) {
            float4 av = *(const float4*)&As[kk][ty << 2];
            float4 wv = *(const float4*)&Ws[kk][tx << 2];
            float a4[4] = {av.x, av.y, av.z, av.w};
            float w4[4] = {wv.x, wv.y, wv.z, wv.w};
#pragma unroll
            for (int i = 0; i < 4; ++i)
#pragma unroll
                for (int j = 0; j < 4; ++j)
                    acc[i][j] += a4[i] * w4[j];
        }
    }

#pragma unroll
    for (int i = 0; i < 4; ++i) {
        int r = bm + (ty << 2) + i;
        if (r >= M) continue;
#pragma unroll
        for (int j = 0; j < 4; ++j) {
            int c = bn + (tx << 2) + j;
            if (c >= N) continue;
            float v = acc[i][j];
            if (EPI == 1 || EPI == 2) v += bias[c];
            if (EPI == 2) v = softplusf_(v);
            if (EPI == 3) v += resid[(size_t)r * ldc + c];
            C[(size_t)r * ldc + c] = v;
        }
    }
}

// ---------------- layernorm over last dim (=384), wave per row ----------------
__global__ __launch_bounds__(256) void ln_rows(
    const float* __restrict__ x, const float* __restrict__ w,
    const float* __restrict__ b, float* __restrict__ out, int rows)
{
    int wave = threadIdx.x >> 6, lane = threadIdx.x & 63;
    int row = blockIdx.x * 4 + wave;
    if (row >= rows) return;
    const float* xr = x + (size_t)row * DMODEL;
    float v[6];
    float s = 0.f, ss = 0.f;
#pragma unroll
    for (int j = 0; j < 6; ++j) {
        v[j] = xr[lane + 64 * j];
        s += v[j];
        ss += v[j] * v[j];
    }
#pragma unroll
    for (int m = 1; m < 64; m <<= 1) {
        s  += __shfl_xor(s, m);
        ss += __shfl_xor(ss, m);
    }
    float mean = s * (1.f / DMODEL);
    float var  = ss * (1.f / DMODEL) - mean * mean;
    float rstd = rsqrtf(var + 1e-5f);
    float* orow = out + (size_t)row * DMODEL;
#pragma unroll
    for (int j = 0; j < 6; ++j) {
        int c = lane + 64 * j;
        orow[c] = (v[j] - mean) * rstd * w[c] + b[c];
    }
}

// ---------------- causal depthwise conv1d (K=4) + bias + SiLU ----------------
__global__ void dwconv_silu(const float* __restrict__ xz, const float* __restrict__ cw,
                            const float* __restrict__ cb, float* __restrict__ out, int total)
{
    int idx = blockIdx.x * 256 + threadIdx.x;
    if (idx >= total) return;
    int d = idx % DINNER;
    int l = (idx / DINNER) & 255;
    int b = idx / (DINNER * 256);
    const float* src = xz + (size_t)(b * 256) * 1536 + d;
    const float* wv = cw + d * 4;
    float acc = cb[d];
#pragma unroll
    for (int k = 0; k < 4; ++k) {
        int ls = l - 3 + k;
        if (ls >= 0) acc += src[(size_t)ls * 1536] * wv[k];
    }
    out[idx] = siluf_(acc);
}

// ================= chunked selective scan =================
// Recurrence per (b,d,n): h <- h*exp(dt*a) + dt*x*B ; y = sum_n h*C + x*D
// Chunk decay: prod_t exp(dt_t*a) = exp(a * sum_t dt_t)  -> only Σdt needed.

// pass1: local scan per chunk from h=0; emit S[b,c,n,d] (chunk end state) and dtsum[b,c,d]
__global__ __launch_bounds__(256) void scan_pass1(
    const float* __restrict__ dt, const float* __restrict__ xb,
    const float* __restrict__ proj, const float* __restrict__ A_log,
    float* __restrict__ S, float* __restrict__ dtsum)
{
    int d = blockIdx.x * 256 + threadIdx.x;
    int c = blockIdx.y, b = blockIdx.z;
    int tid = threadIdx.x;
    __shared__ float sB[LCH][NSTATE];
    {
        int s = tid >> 4, n = tid & 15;
        sB[s][n] = proj[((size_t)(b * LSEQ + c * LCH + s)) * 80 + RLOW + n];
    }
    __syncthreads();
    float a[NSTATE], h[NSTATE];
#pragma unroll
    for (int n = 0; n < NSTATE; ++n) {
        a[n] = -__expf(A_log[(size_t)d * NSTATE + n]);
        h[n] = 0.f;
    }
    float dts = 0.f;
#pragma unroll
    for (int s = 0; s < LCH; ++s) {
        size_t off = ((size_t)(b * LSEQ + c * LCH + s)) * DINNER + d;
        float dtv = dt[off], xv = xb[off];
        dts += dtv;
        float dtx = dtv * xv;
#pragma unroll
        for (int n = 0; n < NSTATE; ++n)
            h[n] = h[n] * __expf(dtv * a[n]) + dtx * sB[s][n];
    }
    dtsum[((size_t)b * CCH + c) * DINNER + d] = dts;
#pragma unroll
    for (int n = 0; n < NSTATE; ++n)
        S[(((size_t)(b * CCH + c) * NSTATE) + n) * DINNER + d] = h[n];
}

// combine: per (b,d,n) sequential prefix over chunks; IN-PLACE: S becomes chunk-START state
__global__ __launch_bounds__(256) void scan_combine(
    const float* __restrict__ A_log, const float* __restrict__ dtsum,
    float* __restrict__ S)
{
    int d = blockIdx.x * 256 + threadIdx.x;
    int n = blockIdx.y, b = blockIdx.z;
    float a = -__expf(A_log[(size_t)d * NSTATE + n]);
    float h = 0.f;
#pragma unroll
    for (int c = 0; c < CCH; ++c) {
        size_t idx = (((size_t)(b * CCH + c) * NSTATE) + n) * DINNER + d;
        float loc = S[idx];
        S[idx] = h;
        h = h * __expf(a * dtsum[((size_t)b * CCH + c) * DINNER + d]) + loc;
    }
}

// pass2: local scan seeded with chunk-start state; emit y with fused silu(z) gate
__global__ __launch_bounds__(256) void scan_pass2(
    const float* __restrict__ dt, const float* __restrict__ xb,
    const float* __restrict__ proj, const float* __restrict__ A_log,
    const float* __restrict__ Dvec, const float* __restrict__ S,
    const float* __restrict__ xz, float* __restrict__ y)
{
    int d = blockIdx.x * 256 + threadIdx.x;
    int c = blockIdx.y, b = blockIdx.z;
    int tid = threadIdx.x;
    __shared__ float sB[LCH][NSTATE], sC[LCH][NSTATE];
    {
        int s = tid >> 4, n = tid & 15;
        size_t base = ((size_t)(b * LSEQ + c * LCH + s)) * 80 + RLOW;
        sB[s][n] = proj[base + n];
        sC[s][n] = proj[base + NSTATE + n];
    }
    __syncthreads();
    float a[NSTATE], h[NSTATE];
#pragma unroll
    for (int n = 0; n < NSTATE; ++n) {
        a[n] = -__expf(A_log[(size_t)d * NSTATE + n]);
        h[n] = S[(((size_t)(b * CCH + c) * NSTATE) + n) * DINNER + d];
    }
    float Dv = Dvec[d];
#pragma unroll
    for (int s = 0; s < LCH; ++s) {
        size_t row = (size_t)(b * LSEQ + c * LCH + s);
        size_t off = row * DINNER + d;
        float dtv = dt[off], xv = xb[off];
        float dtx = dtv * xv;
        float yv = 0.f;
#pragma unroll
        for (int n = 0; n < NSTATE; ++n) {
            h[n] = h[n] * __expf(dtv * a[n]) + dtx * sB[s][n];
            yv += h[n] * sC[s][n];
        }
        float z = xz[row * 1536 + DINNER + d];
        y[off] = (yv + xv * Dv) * siluf_(z);
    }
}

// ---------------- mean pool over L ----------------
__global__ void mean_pool(const float* __restrict__ x, float* __restrict__ out)
{
    int idx = blockIdx.x * 256 + threadIdx.x;
    if (idx >= BATCH * DMODEL) return;
    int b = idx / DMODEL, m = idx % DMODEL;
    const float* p = x + (size_t)(b * LSEQ) * DMODEL + m;
    float s = 0.f;
    for (int l = 0; l < LSEQ; ++l) s += p[(size_t)l * DMODEL];
    out[idx] = s * (1.f / LSEQ);
}

// ---------------- host launch ----------------
static inline int ceil_div(int a, int b) { return (a + b - 1) / b; }

extern "C" void kernel_launch(void* const* d_in, const int* in_sizes, int n_in,
                              void* d_out, int out_size, void* d_ws, size_t ws_size,
                              hipStream_t stream)
{
    const float* x        = (const float*)d_in[0];
    const float* patch_w  = (const float*)d_in[1];
    const float* patch_b  = (const float*)d_in[2];
    const float* norm_w   = (const float*)d_in[3];
    const float* norm_b   = (const float*)d_in[4];
    const float* in_proj  = (const float*)d_in[5];
    const float* conv_w   = (const float*)d_in[6];
    const float* conv_b   = (const float*)d_in[7];
    const float* A_log    = (const float*)d_in[8];
    const float* D_ssm    = (const float*)d_in[9];
    const float* xproj_w  = (const float*)d_in[10];
    const float* dtproj_w = (const float*)d_in[11];
    const float* dtproj_b = (const float*)d_in[12];
    const float* out_proj = (const float*)d_in[13];
    const float* fnorm_w  = (const float*)d_in[14];
    const float* fnorm_b  = (const float*)d_in[15];
    const float* cls_w    = (const float*)d_in[16];
    const float* cls_b    = (const float*)d_in[17];
    float* out = (float*)d_out;

    float* ws = (float*)d_ws;
    const size_t OFF_XZ   = 0;
    const size_t OFF_T    = OFF_XZ + (size_t)NROWS * 1536;
    const size_t OFF_XN   = OFF_T + (size_t)NROWS * DMODEL;
    const size_t OFF_XB   = OFF_XN + (size_t)NROWS * DMODEL;
    const size_t OFF_PROJ = OFF_XB + (size_t)NROWS * DINNER;
    const size_t OFF_DT   = OFF_PROJ + (size_t)NROWS * 80;
    const size_t OFF_POOL = OFF_DT + (size_t)NROWS * DINNER;
    const size_t OFF_S    = OFF_POOL + (size_t)BATCH * DMODEL;
    const size_t OFF_DSUM = OFF_S + (size_t)BATCH * CCH * NSTATE * DINNER;

    float* col    = ws + OFF_XZ;
    float* t      = ws + OFF_T;
    float* xn     = ws + OFF_XN;
    float* xz     = ws + OFF_XZ;
    float* xb     = ws + OFF_XB;
    float* proj   = ws + OFF_PROJ;
    float* dtbuf  = ws + OFF_DT;
    float* pooled = ws + OFF_POOL;
    float* Sbuf   = ws + OFF_S;
    float* dsum   = ws + OFF_DSUM;

    // 1. im2col + patch-embed GEMM  -> t (8192, 384)
    {
        int total = NROWS * KPATCH;
        im2col_patch<<<ceil_div(total, 256), 256, 0, stream>>>(x, col, total);
        dim3 g(ceil_div(DMODEL, 64), ceil_div(NROWS, 64));
        gemm_tn<1><<<g, 256, 0, stream>>>(col, KPATCH, patch_w, KPATCH, t, DMODEL,
                                          NROWS, DMODEL, KPATCH, patch_b, nullptr);
    }

    // 2. mamba blocks
    for (int l = 0; l < NLAYER; ++l) {
        const float* nw  = norm_w   + (size_t)l * DMODEL;
        const float* nb  = norm_b   + (size_t)l * DMODEL;
        const float* ipw = in_proj  + (size_t)l * 2 * DINNER * DMODEL;
        const float* cw  = conv_w   + (size_t)l * DINNER * KCONV;
        const float* cb  = conv_b   + (size_t)l * DINNER;
        const float* al  = A_log    + (size_t)l * DINNER * NSTATE;
        const float* dp  = D_ssm    + (size_t)l * DINNER;
        const float* xw  = xproj_w  + (size_t)l * 80 * DINNER;
        const float* dtw = dtproj_w + (size_t)l * DINNER * RLOW;
        const float* dtb = dtproj_b + (size_t)l * DINNER;
        const float* opw = out_proj + (size_t)l * DMODEL * DINNER;

        // LN
        ln_rows<<<NROWS / 4, 256, 0, stream>>>(t, nw, nb, xn, NROWS);
        // in_proj: (8192,384)@(1536,384)^T -> xz (8192,1536)
        {
            dim3 g(ceil_div(2 * DINNER, 64), ceil_div(NROWS, 64));
            gemm_tn<0><<<g, 256, 0, stream>>>(xn, DMODEL, ipw, DMODEL, xz, 2 * DINNER,
                                              NROWS, 2 * DINNER, DMODEL, nullptr, nullptr);
        }
        // causal depthwise conv + silu -> xb (8192,768)
        {
            int total = NROWS * DINNER;
            dwconv_silu<<<ceil_div(total, 256), 256, 0, stream>>>(xz, cw, cb, xb, total);
        }
        // xproj: (8192,768)@(80,768)^T -> proj (8192,80)
        {
            dim3 g(ceil_div(80, 64), ceil_div(NROWS, 64));
            gemm_tn<0><<<g, 256, 0, stream>>>(xb, DINNER, xw, DINNER, proj, 80,
                                              NROWS, 80, DINNER, nullptr, nullptr);
        }
        // dtproj + softplus: (8192,48)@(768,48)^T -> dtbuf (8192,768)
        {
            dim3 g(ceil_div(DINNER, 64), ceil_div(NROWS, 64));
            gemm_tn<2><<<g, 256, 0, stream>>>(proj, 80, dtw, RLOW, dtbuf, DINNER,
                                              NROWS, DINNER, RLOW, dtb, nullptr);
        }
        // chunked scan: pass1 -> combine -> pass2 (gate fused); y in-place over dtbuf
        {
            dim3 g1(DINNER / 256, CCH, BATCH);
            scan_pass1<<<g1, 256, 0, stream>>>(dtbuf, xb, proj, al, Sbuf, dsum);
            dim3 g2(DINNER / 256, NSTATE, BATCH);
            scan_combine<<<g2, 256, 0, stream>>>(al, dsum, Sbuf);
            scan_pass2<<<g1, 256, 0, stream>>>(dtbuf, xb, proj, al, dp, Sbuf, xz, dtbuf);
        }
        // out_proj + residual: (8192,768)@(384,768)^T + t -> t
        {
            dim3 g(ceil_div(DMODEL, 64), ceil_div(NROWS, 64));
            gemm_tn<3><<<g, 256, 0, stream>>>(dtbuf, DINNER, opw, DINNER, t, DMODEL,
                                              NROWS, DMODEL, DINNER, nullptr, t);
        }
    }

    // 3. final LN -> xn, mean pool -> pooled, classifier -> out
    ln_rows<<<NROWS / 4, 256, 0, stream>>>(t, fnorm_w, fnorm_b, xn, NROWS);
    mean_pool<<<ceil_div(BATCH * DMODEL, 256), 256, 0, stream>>>(xn, pooled);
    {
        dim3 g(ceil_div(NCLS, 64), ceil_div(BATCH, 64));
        gemm_tn<1><<<g, 256, 0, stream>>>(pooled, DMODEL, cls_w, DMODEL, out, NCLS,
                                          BATCH, NCLS, DMODEL, cls_b, nullptr);
    }
}

// Round 3
// 1063.377 us; speedup vs baseline: 2.5018x; 1.7365x over previous
//
#include <hip/hip_runtime.h>
#include <cstdint>
#include <cstddef>

// ---------------- constants ----------------
#define BATCH 32
#define LSEQ  256
#define DMODEL 384
#define DINNER 768
#define NSTATE 16
#define RLOW   48
#define KCONV  4
#define NCLS   1000
#define NLAYER 4
#define KPATCH 588    // 3*14*14
#define KPATCH_PAD 640
#define NROWS  (BATCH*LSEQ)   // 8192
#define CCH 16
#define LCH 16

typedef __bf16 bf16x8 __attribute__((ext_vector_type(8)));
typedef float  f32x4  __attribute__((ext_vector_type(4)));

__device__ __forceinline__ float siluf_(float x)    { return x / (1.f + __expf(-x)); }
__device__ __forceinline__ float softplusf_(float x){ return fmaxf(x, 0.f) + log1pf(__expf(-fabsf(x))); }

__device__ __forceinline__ void gl2lds16(const void* g, void* l) {
    __builtin_amdgcn_global_load_lds(
        (const __attribute__((address_space(1))) unsigned*)g,
        (__attribute__((address_space(3))) unsigned*)l, 16, 0, 0);
}

// ---------------- fp32 -> bf16 conversion ----------------
__global__ void f2b(const float* __restrict__ s, __bf16* __restrict__ d, int n) {
    int i = blockIdx.x * 256 + threadIdx.x;
    if (i < n) d[i] = (__bf16)s[i];
}

// patch weight: (384,588) -> bf16 (384,640) zero-padded K
__global__ void padw_patch(const float* __restrict__ s, __bf16* __restrict__ d) {
    int i = blockIdx.x * 256 + threadIdx.x;
    if (i >= DMODEL * KPATCH_PAD) return;
    int k = i % KPATCH_PAD, r = i / KPATCH_PAD;
    d[i] = (k < KPATCH) ? (__bf16)s[r * KPATCH + k] : (__bf16)0.f;
}

// ---------------- im2col (bf16, K padded to 640) ----------------
__global__ void im2col_bf(const float* __restrict__ x, __bf16* __restrict__ col) {
    int idx = blockIdx.x * 256 + threadIdx.x;
    if (idx >= NROWS * KPATCH_PAD) return;
    int k = idx % KPATCH_PAD;
    int row = idx / KPATCH_PAD;
    if (k >= KPATCH) { col[idx] = (__bf16)0.f; return; }
    int b = row >> 8, l = row & 255;
    int py = l >> 4, px = l & 15;
    int c = k / 196;
    int rem = k % 196;
    int i = rem / 14, j = rem % 14;
    col[idx] = (__bf16)x[(((size_t)(b * 3 + c) * 224) + py * 14 + i) * 224 + px * 14 + j];
}

// ---------------- bf16 MFMA GEMM: C[M,N](f32) = A[M,K](bf16) * W[N,K](bf16)^T ----------------
// 128x128 tile, BK=32, 4 waves 2x2, each wave 4x4 of 16x16x32 MFMA.
// Requires M%128==0, N%128==0 (or exact multiple tiles), K%32==0, 16B-aligned rows.
// EPI: 0 = none, 1 = +bias, 3 = +resid
template <int EPI>
__global__ __launch_bounds__(256) void mfma_gemm(
    const __bf16* __restrict__ A, int lda,
    const __bf16* __restrict__ W, int ldw,
    float* __restrict__ C, int ldc,
    int K,
    const float* __restrict__ bias,
    const float* __restrict__ resid)
{
    __shared__ __bf16 As[128 * 32];
    __shared__ __bf16 Bs[128 * 32];
    const int t = threadIdx.x;
    const int w = t >> 6;          // wave 0..3
    const int lane = t & 63;
    const int quad = lane >> 4;    // 0..3
    const int r16 = lane & 15;
    const int wm = w >> 1, wn = w & 1;
    const int bm = blockIdx.y * 128, bn = blockIdx.x * 128;

    // staging addressing: per wave-issue q (2 for A, 2 for B): 16 rows x 32 k
    const int srow = (lane >> 2);        // 0..15
    const int skoff = (lane & 3) * 8;    // 0,8,16,24

    f32x4 acc[4][4] = {};

    for (int k0 = 0; k0 < K; k0 += 32) {
        __syncthreads();
#pragma unroll
        for (int q = 0; q < 2; ++q) {
            int arow = w * 32 + q * 16;
            gl2lds16(A + (size_t)(bm + arow + srow) * lda + k0 + skoff, As + arow * 32);
            gl2lds16(W + (size_t)(bn + arow + srow) * ldw + k0 + skoff, Bs + arow * 32);
        }
        __syncthreads();

        bf16x8 af[4], bfr[4];
#pragma unroll
        for (int i = 0; i < 4; ++i)
            af[i] = *(const bf16x8*)(As + (wm * 64 + i * 16 + r16) * 32 + quad * 8);
#pragma unroll
        for (int j = 0; j < 4; ++j)
            bfr[j] = *(const bf16x8*)(Bs + (wn * 64 + j * 16 + r16) * 32 + quad * 8);
#pragma unroll
        for (int i = 0; i < 4; ++i)
#pragma unroll
            for (int j = 0; j < 4; ++j)
                acc[i][j] = __builtin_amdgcn_mfma_f32_16x16x32_bf16(af[i], bfr[j], acc[i][j], 0, 0, 0);
    }

    // epilogue: C row = bm + wm*64 + i*16 + quad*4 + r ; col = bn + wn*64 + j*16 + r16
#pragma unroll
    for (int i = 0; i < 4; ++i) {
#pragma unroll
        for (int r = 0; r < 4; ++r) {
            int row = bm + wm * 64 + i * 16 + quad * 4 + r;
            float* crow = C + (size_t)row * ldc;
            const float* rrow = (EPI == 3) ? (resid + (size_t)row * ldc) : nullptr;
#pragma unroll
            for (int j = 0; j < 4; ++j) {
                int col = bn + wn * 64 + j * 16 + r16;
                float v = acc[i][j][r];
                if (EPI == 1) v += bias[col];
                if (EPI == 3) v += rrow[col];
                crow[col] = v;
            }
        }
    }
}

// ---------------- fp32 tiled GEMM (small shapes): C = A * W^T ----------------
// EPI: 0 none, 1 +bias, 2 softplus(+bias)
template <int EPI>
__global__ __launch_bounds__(256) void gemm_tn(
    const float* __restrict__ A, int lda,
    const float* __restrict__ W, int ldw,
    float* __restrict__ C, int ldc,
    int M, int N, int K,
    const float* __restrict__ bias)
{
    __shared__ __align__(16) float As[16][68];
    __shared__ __align__(16) float Ws[16][68];
    const int t  = threadIdx.x;
    const int bm = blockIdx.y * 64, bn = blockIdx.x * 64;
    const int tx = t & 15, ty = t >> 4;
    const int lr = t >> 2;
    const int lk = (t & 3) << 2;

    float acc[4][4] = {};

    for (int k0 = 0; k0 < K; k0 += 16) {
        float4 va = {0.f, 0.f, 0.f, 0.f};
        {
            int row = bm + lr, kb = k0 + lk;
            if (row < M && kb < K) {
                const float* p = A + (size_t)row * lda + kb;
                if (kb + 3 < K) va = *(const float4*)p;
                else {
                    va.x = p[0];
                    if (kb + 1 < K) va.y = p[1];
                    if (kb + 2 < K) va.z = p[2];
                }
            }
        }
        float4 vw = {0.f, 0.f, 0.f, 0.f};
        {
            int col = bn + lr, kb = k0 + lk;
            if (col < N && kb < K) {
                const float* p = W + (size_t)col * ldw + kb;
                if (kb + 3 < K) vw = *(const float4*)p;
                else {
                    vw.x = p[0];
                    if (kb + 1 < K) vw.y = p[1];
                    if (kb + 2 < K) vw.z = p[2];
                }
            }
        }
        __syncthreads();
        As[lk + 0][lr] = va.x; As[lk + 1][lr] = va.y; As[lk + 2][lr] = va.z; As[lk + 3][lr] = va.w;
        Ws[lk + 0][lr] = vw.x; Ws[lk + 1][lr] = vw.y; Ws[lk + 2][lr] = vw.z; Ws[lk + 3][lr] = vw.w;
        __syncthreads();

#pragma unroll
        for (int kk = 0; kk < 16; ++kk) {
            float4 av = *(const float4*)&As[kk][ty << 2];
            float4 wv = *(const float4*)&Ws[kk][tx << 2];
            float a4[4] = {av.x, av.y, av.z, av.w};
            float w4[4] = {wv.x, wv.y, wv.z, wv.w};
#pragma unroll
            for (int i = 0; i < 4; ++i)
#pragma unroll
                for (int j = 0; j < 4; ++j)
                    acc[i][j] += a4[i] * w4[j];
        }
    }

#pragma unroll
    for (int i = 0; i < 4; ++i) {
        int r = bm + (ty << 2) + i;
        if (r >= M) continue;
#pragma unroll
        for (int j = 0; j < 4; ++j) {
            int c = bn + (tx << 2) + j;
            if (c >= N) continue;
            float v = acc[i][j];
            if (EPI == 1 || EPI == 2) v += bias[c];
            if (EPI == 2) v = softplusf_(v);
            C[(size_t)r * ldc + c] = v;
        }
    }
}

// ---------------- layernorm over last dim (=384), wave per row ----------------
template <typename OT>
__global__ __launch_bounds__(256) void ln_rows(
    const float* __restrict__ x, const float* __restrict__ w,
    const float* __restrict__ b, OT* __restrict__ out, int rows)
{
    int wave = threadIdx.x >> 6, lane = threadIdx.x & 63;
    int row = blockIdx.x * 4 + wave;
    if (row >= rows) return;
    const float* xr = x + (size_t)row * DMODEL;
    float v[6];
    float s = 0.f, ss = 0.f;
#pragma unroll
    for (int j = 0; j < 6; ++j) {
        v[j] = xr[lane + 64 * j];
        s += v[j];
        ss += v[j] * v[j];
    }
#pragma unroll
    for (int m = 1; m < 64; m <<= 1) {
        s  += __shfl_xor(s, m);
        ss += __shfl_xor(ss, m);
    }
    float mean = s * (1.f / DMODEL);
    float var  = ss * (1.f / DMODEL) - mean * mean;
    float rstd = rsqrtf(var + 1e-5f);
    OT* orow = out + (size_t)row * DMODEL;
#pragma unroll
    for (int j = 0; j < 6; ++j) {
        int c = lane + 64 * j;
        orow[c] = (OT)((v[j] - mean) * rstd * w[c] + b[c]);
    }
}

// ---------------- causal depthwise conv1d (K=4) + bias + SiLU ----------------
__global__ void dwconv_silu(const float* __restrict__ xz, const float* __restrict__ cw,
                            const float* __restrict__ cb, float* __restrict__ out, int total)
{
    int idx = blockIdx.x * 256 + threadIdx.x;
    if (idx >= total) return;
    int d = idx % DINNER;
    int l = (idx / DINNER) & 255;
    int b = idx / (DINNER * 256);
    const float* src = xz + (size_t)(b * 256) * 1536 + d;
    const float* wv = cw + d * 4;
    float acc = cb[d];
#pragma unroll
    for (int k = 0; k < 4; ++k) {
        int ls = l - 3 + k;
        if (ls >= 0) acc += src[(size_t)ls * 1536] * wv[k];
    }
    out[idx] = siluf_(acc);
}

// ================= chunked selective scan =================
__global__ __launch_bounds__(256) void scan_pass1(
    const float* __restrict__ dt, const float* __restrict__ xb,
    const float* __restrict__ proj, const float* __restrict__ A_log,
    float* __restrict__ S, float* __restrict__ dtsum)
{
    int d = blockIdx.x * 256 + threadIdx.x;
    int c = blockIdx.y, b = blockIdx.z;
    int tid = threadIdx.x;
    __shared__ float sB[LCH][NSTATE];
    {
        int s = tid >> 4, n = tid & 15;
        sB[s][n] = proj[((size_t)(b * LSEQ + c * LCH + s)) * 80 + RLOW + n];
    }
    __syncthreads();
    float a[NSTATE], h[NSTATE];
#pragma unroll
    for (int n = 0; n < NSTATE; ++n) {
        a[n] = -__expf(A_log[(size_t)d * NSTATE + n]);
        h[n] = 0.f;
    }
    float dts = 0.f;
#pragma unroll
    for (int s = 0; s < LCH; ++s) {
        size_t off = ((size_t)(b * LSEQ + c * LCH + s)) * DINNER + d;
        float dtv = dt[off], xv = xb[off];
        dts += dtv;
        float dtx = dtv * xv;
#pragma unroll
        for (int n = 0; n < NSTATE; ++n)
            h[n] = h[n] * __expf(dtv * a[n]) + dtx * sB[s][n];
    }
    dtsum[((size_t)b * CCH + c) * DINNER + d] = dts;
#pragma unroll
    for (int n = 0; n < NSTATE; ++n)
        S[(((size_t)(b * CCH + c) * NSTATE) + n) * DINNER + d] = h[n];
}

__global__ __launch_bounds__(256) void scan_combine(
    const float* __restrict__ A_log, const float* __restrict__ dtsum,
    float* __restrict__ S)
{
    int d = blockIdx.x * 256 + threadIdx.x;
    int n = blockIdx.y, b = blockIdx.z;
    float a = -__expf(A_log[(size_t)d * NSTATE + n]);
    float h = 0.f;
#pragma unroll
    for (int c = 0; c < CCH; ++c) {
        size_t idx = (((size_t)(b * CCH + c) * NSTATE) + n) * DINNER + d;
        float loc = S[idx];
        S[idx] = h;
        h = h * __expf(a * dtsum[((size_t)b * CCH + c) * DINNER + d]) + loc;
    }
}

// pass2: seeded local scan; fused silu(z) gate; bf16 output for out_proj
__global__ __launch_bounds__(256) void scan_pass2(
    const float* __restrict__ dt, const float* __restrict__ xb,
    const float* __restrict__ proj, const float* __restrict__ A_log,
    const float* __restrict__ Dvec, const float* __restrict__ S,
    const float* __restrict__ xz, __bf16* __restrict__ y)
{
    int d = blockIdx.x * 256 + threadIdx.x;
    int c = blockIdx.y, b = blockIdx.z;
    int tid = threadIdx.x;
    __shared__ float sB[LCH][NSTATE], sC[LCH][NSTATE];
    {
        int s = tid >> 4, n = tid & 15;
        size_t base = ((size_t)(b * LSEQ + c * LCH + s)) * 80 + RLOW;
        sB[s][n] = proj[base + n];
        sC[s][n] = proj[base + NSTATE + n];
    }
    __syncthreads();
    float a[NSTATE], h[NSTATE];
#pragma unroll
    for (int n = 0; n < NSTATE; ++n) {
        a[n] = -__expf(A_log[(size_t)d * NSTATE + n]);
        h[n] = S[(((size_t)(b * CCH + c) * NSTATE) + n) * DINNER + d];
    }
    float Dv = Dvec[d];
#pragma unroll
    for (int s = 0; s < LCH; ++s) {
        size_t row = (size_t)(b * LSEQ + c * LCH + s);
        size_t off = row * DINNER + d;
        float dtv = dt[off], xv = xb[off];
        float dtx = dtv * xv;
        float yv = 0.f;
#pragma unroll
        for (int n = 0; n < NSTATE; ++n) {
            h[n] = h[n] * __expf(dtv * a[n]) + dtx * sB[s][n];
            yv += h[n] * sC[s][n];
        }
        float z = xz[row * 1536 + DINNER + d];
        y[off] = (__bf16)((yv + xv * Dv) * siluf_(z));
    }
}

// ---------------- mean pool over L ----------------
__global__ void mean_pool(const float* __restrict__ x, float* __restrict__ out)
{
    int idx = blockIdx.x * 256 + threadIdx.x;
    if (idx >= BATCH * DMODEL) return;
    int b = idx / DMODEL, m = idx % DMODEL;
    const float* p = x + (size_t)(b * LSEQ) * DMODEL + m;
    float s = 0.f;
    for (int l = 0; l < LSEQ; ++l) s += p[(size_t)l * DMODEL];
    out[idx] = s * (1.f / LSEQ);
}

// ---------------- host launch ----------------
static inline int ceil_div(int a, int b) { return (a + b - 1) / b; }

extern "C" void kernel_launch(void* const* d_in, const int* in_sizes, int n_in,
                              void* d_out, int out_size, void* d_ws, size_t ws_size,
                              hipStream_t stream)
{
    const float* x        = (const float*)d_in[0];
    const float* patch_w  = (const float*)d_in[1];
    const float* patch_b  = (const float*)d_in[2];
    const float* norm_w   = (const float*)d_in[3];
    const float* norm_b   = (const float*)d_in[4];
    const float* in_proj  = (const float*)d_in[5];
    const float* conv_w   = (const float*)d_in[6];
    const float* conv_b   = (const float*)d_in[7];
    const float* A_log    = (const float*)d_in[8];
    const float* D_ssm    = (const float*)d_in[9];
    const float* xproj_w  = (const float*)d_in[10];
    const float* dtproj_w = (const float*)d_in[11];
    const float* dtproj_b = (const float*)d_in[12];
    const float* out_proj = (const float*)d_in[13];
    const float* fnorm_w  = (const float*)d_in[14];
    const float* fnorm_b  = (const float*)d_in[15];
    const float* cls_w    = (const float*)d_in[16];
    const float* cls_b    = (const float*)d_in[17];
    float* out = (float*)d_out;

    float* ws = (float*)d_ws;
    // float-unit offsets
    const size_t OFF_XZ   = 0;                                    // 12,582,912
    const size_t OFF_T    = OFF_XZ + (size_t)NROWS * 1536;
    const size_t OFF_XB   = OFF_T  + (size_t)NROWS * DMODEL;
    const size_t OFF_PROJ = OFF_XB + (size_t)NROWS * DINNER;
    const size_t OFF_DT   = OFF_PROJ + (size_t)NROWS * 80;
    const size_t OFF_S    = OFF_DT + (size_t)NROWS * DINNER;
    const size_t OFF_DSUM = OFF_S  + (size_t)BATCH * CCH * NSTATE * DINNER;
    const size_t OFF_POOL = OFF_DSUM + (size_t)BATCH * CCH * DINNER;
    const size_t OFF_XNBF = OFF_POOL + (size_t)BATCH * DMODEL;    // bf16 region (floats*2)
    const size_t OFF_YBF  = OFF_XNBF + (size_t)NROWS * DMODEL / 2;
    const size_t OFF_WIP  = OFF_YBF + (size_t)NROWS * DINNER / 2;
    const size_t OFF_WOP  = OFF_WIP + (size_t)NLAYER * 2 * DINNER * DMODEL / 2;
    const size_t OFF_WP   = OFF_WOP + (size_t)NLAYER * DMODEL * DINNER / 2;

    float*  xz     = ws + OFF_XZ;
    float*  t      = ws + OFF_T;
    float*  xb     = ws + OFF_XB;
    float*  proj   = ws + OFF_PROJ;
    float*  dtbuf  = ws + OFF_DT;
    float*  Sbuf   = ws + OFF_S;
    float*  dsum   = ws + OFF_DSUM;
    float*  pooled = ws + OFF_POOL;
    __bf16* xnbf   = (__bf16*)(ws + OFF_XNBF);
    __bf16* ybf    = (__bf16*)(ws + OFF_YBF);
    __bf16* wip    = (__bf16*)(ws + OFF_WIP);
    __bf16* wop    = (__bf16*)(ws + OFF_WOP);
    __bf16* wpp    = (__bf16*)(ws + OFF_WP);
    __bf16* colbf  = ybf;   // im2col aliases ybf (disjoint liveness)

    // 0. weight conversions (fp32 -> bf16)
    {
        int nip = NLAYER * 2 * DINNER * DMODEL;
        f2b<<<ceil_div(nip, 256), 256, 0, stream>>>(in_proj, wip, nip);
        int nop = NLAYER * DMODEL * DINNER;
        f2b<<<ceil_div(nop, 256), 256, 0, stream>>>(out_proj, wop, nop);
        padw_patch<<<ceil_div(DMODEL * KPATCH_PAD, 256), 256, 0, stream>>>(patch_w, wpp);
    }

    // 1. im2col + patch-embed MFMA GEMM -> t (8192,384)
    {
        im2col_bf<<<ceil_div(NROWS * KPATCH_PAD, 256), 256, 0, stream>>>(x, colbf);
        dim3 g(DMODEL / 128, NROWS / 128);
        mfma_gemm<1><<<g, 256, 0, stream>>>(colbf, KPATCH_PAD, wpp, KPATCH_PAD,
                                            t, DMODEL, KPATCH_PAD, patch_b, nullptr);
    }

    // 2. mamba blocks
    for (int l = 0; l < NLAYER; ++l) {
        const float* nw  = norm_w   + (size_t)l * DMODEL;
        const float* nb  = norm_b   + (size_t)l * DMODEL;
        const __bf16* ipw = wip + (size_t)l * 2 * DINNER * DMODEL;
        const float* cw  = conv_w   + (size_t)l * DINNER * KCONV;
        const float* cb  = conv_b   + (size_t)l * DINNER;
        const float* al  = A_log    + (size_t)l * DINNER * NSTATE;
        const float* dp  = D_ssm    + (size_t)l * DINNER;
        const float* xw  = xproj_w  + (size_t)l * 80 * DINNER;
        const float* dtw = dtproj_w + (size_t)l * DINNER * RLOW;
        const float* dtb = dtproj_b + (size_t)l * DINNER;
        const __bf16* opw = wop + (size_t)l * DMODEL * DINNER;

        // LN -> bf16
        ln_rows<__bf16><<<NROWS / 4, 256, 0, stream>>>(t, nw, nb, xnbf, NROWS);
        // in_proj (MFMA): (8192,384)bf16 @ (1536,384)bf16^T -> xz fp32
        {
            dim3 g(2 * DINNER / 128, NROWS / 128);
            mfma_gemm<0><<<g, 256, 0, stream>>>(xnbf, DMODEL, ipw, DMODEL,
                                                xz, 2 * DINNER, DMODEL, nullptr, nullptr);
        }
        // causal depthwise conv + silu -> xb
        {
            int total = NROWS * DINNER;
            dwconv_silu<<<ceil_div(total, 256), 256, 0, stream>>>(xz, cw, cb, xb, total);
        }
        // xproj (fp32): (8192,768)@(80,768)^T -> proj
        {
            dim3 g(ceil_div(80, 64), ceil_div(NROWS, 64));
            gemm_tn<0><<<g, 256, 0, stream>>>(xb, DINNER, xw, DINNER, proj, 80,
                                              NROWS, 80, DINNER, nullptr);
        }
        // dtproj + softplus (fp32): (8192,48)@(768,48)^T -> dtbuf
        {
            dim3 g(ceil_div(DINNER, 64), ceil_div(NROWS, 64));
            gemm_tn<2><<<g, 256, 0, stream>>>(proj, 80, dtw, RLOW, dtbuf, DINNER,
                                              NROWS, DINNER, RLOW, dtb);
        }
        // chunked scan; gated bf16 y -> ybf
        {
            dim3 g1(DINNER / 256, CCH, BATCH);
            scan_pass1<<<g1, 256, 0, stream>>>(dtbuf, xb, proj, al, Sbuf, dsum);
            dim3 g2(DINNER / 256, NSTATE, BATCH);
            scan_combine<<<g2, 256, 0, stream>>>(al, dsum, Sbuf);
            scan_pass2<<<g1, 256, 0, stream>>>(dtbuf, xb, proj, al, dp, Sbuf, xz, ybf);
        }
        // out_proj (MFMA) + residual: (8192,768)bf16 @ (384,768)bf16^T + t -> t
        {
            dim3 g(DMODEL / 128, NROWS / 128);
            mfma_gemm<3><<<g, 256, 0, stream>>>(ybf, DINNER, opw, DINNER,
                                                t, DMODEL, DINNER, nullptr, t);
        }
    }

    // 3. final LN (fp32, into dtbuf) -> mean pool -> classifier (fp32)
    ln_rows<float><<<NROWS / 4, 256, 0, stream>>>(t, fnorm_w, fnorm_b, dtbuf, NROWS);
    mean_pool<<<ceil_div(BATCH * DMODEL, 256), 256, 0, stream>>>(dtbuf, pooled);
    {
        dim3 g(ceil_div(NCLS, 64), ceil_div(BATCH, 64));
        gemm_tn<1><<<g, 256, 0, stream>>>(pooled, DMODEL, cls_w, DMODEL, out, NCLS,
                                          BATCH, NCLS, DMODEL, cls_b);
    }
}

// Round 4
// 938.602 us; speedup vs baseline: 2.8344x; 1.1329x over previous
//
#include <hip/hip_runtime.h>
#include <cstdint>
#include <cstddef>

// ---------------- constants ----------------
#define BATCH 32
#define LSEQ  256
#define DMODEL 384
#define DINNER 768
#define NSTATE 16
#define RLOW   48
#define KCONV  4
#define NCLS   1000
#define NLAYER 4
#define KPATCH 588    // 3*14*14
#define KPATCH_PAD 640
#define NROWS  (BATCH*LSEQ)   // 8192
#define CCH 16
#define LCH 16
#define PROJ_LD 128   // padded xproj output width (80 -> 128)
#define KDT_PAD 64    // padded dtproj K (48 -> 64)

typedef __bf16 bf16x8 __attribute__((ext_vector_type(8)));
typedef float  f32x4  __attribute__((ext_vector_type(4)));

__device__ __forceinline__ float siluf_(float x)    { return x / (1.f + __expf(-x)); }
__device__ __forceinline__ float softplusf_(float x){ return fmaxf(x, 0.f) + log1pf(__expf(-fabsf(x))); }

__device__ __forceinline__ void gl2lds16(const void* g, void* l) {
    __builtin_amdgcn_global_load_lds(
        (const __attribute__((address_space(1))) unsigned*)g,
        (__attribute__((address_space(3))) unsigned*)l, 16, 0, 0);
}

// ---------------- weight prep ----------------
__global__ void f2b(const float* __restrict__ s, __bf16* __restrict__ d, int n) {
    int i = blockIdx.x * 256 + threadIdx.x;
    if (i < n) d[i] = (__bf16)s[i];
}

// patch weight: (384,588) -> bf16 (384,640) zero-padded K
__global__ void padw_patch(const float* __restrict__ s, __bf16* __restrict__ d) {
    int i = blockIdx.x * 256 + threadIdx.x;
    if (i >= DMODEL * KPATCH_PAD) return;
    int k = i % KPATCH_PAD, r = i / KPATCH_PAD;
    d[i] = (k < KPATCH) ? (__bf16)s[r * KPATCH + k] : (__bf16)0.f;
}

// xproj weight: (NL,80,768) -> bf16 (NL,128,768), rows 80..127 zero
__global__ void padw_xp(const float* __restrict__ s, __bf16* __restrict__ d) {
    int i = blockIdx.x * 256 + threadIdx.x;
    if (i >= NLAYER * PROJ_LD * DINNER) return;
    int c = i % DINNER;
    int r = (i / DINNER) % PROJ_LD;
    int l = i / (DINNER * PROJ_LD);
    d[i] = (r < 80) ? (__bf16)s[((size_t)l * 80 + r) * DINNER + c] : (__bf16)0.f;
}

// dtproj weight: (NL,768,48) -> bf16 (NL,768,64), cols 48..63 zero
__global__ void padw_dt(const float* __restrict__ s, __bf16* __restrict__ d) {
    int i = blockIdx.x * 256 + threadIdx.x;
    if (i >= NLAYER * DINNER * KDT_PAD) return;
    int k = i % KDT_PAD;
    int r = (i / KDT_PAD) % DINNER;
    int l = i / (KDT_PAD * DINNER);
    d[i] = (k < RLOW) ? (__bf16)s[((size_t)l * DINNER + r) * RLOW + k] : (__bf16)0.f;
}

// ---------------- im2col (bf16, K padded to 640) ----------------
__global__ void im2col_bf(const float* __restrict__ x, __bf16* __restrict__ col) {
    int idx = blockIdx.x * 256 + threadIdx.x;
    if (idx >= NROWS * KPATCH_PAD) return;
    int k = idx % KPATCH_PAD;
    int row = idx / KPATCH_PAD;
    if (k >= KPATCH) { col[idx] = (__bf16)0.f; return; }
    int b = row >> 8, l = row & 255;
    int py = l >> 4, px = l & 15;
    int c = k / 196;
    int rem = k % 196;
    int i = rem / 14, j = rem % 14;
    col[idx] = (__bf16)x[(((size_t)(b * 3 + c) * 224) + py * 14 + i) * 224 + px * 14 + j];
}

// ---------------- bf16 MFMA GEMM: C[M,N](OT) = A[M,K](bf16) * W[N,K](bf16)^T ----------------
// 128x128 tile, BK=32, 4 waves 2x2, each wave 4x4 of 16x16x32 MFMA.
// Requires M%128==0, N%128==0, K%32==0, 16B-aligned rows.
// EPI: 0 none, 1 +bias, 2 softplus(+bias), 3 +resid(f32)
template <int EPI, typename OT>
__global__ __launch_bounds__(256) void mfma_gemm(
    const __bf16* __restrict__ A, int lda,
    const __bf16* __restrict__ W, int ldw,
    OT* __restrict__ C, int ldc,
    int K,
    const float* __restrict__ bias,
    const float* __restrict__ resid)
{
    __shared__ __bf16 As[128 * 32];
    __shared__ __bf16 Bs[128 * 32];
    const int t = threadIdx.x;
    const int w = t >> 6;
    const int lane = t & 63;
    const int quad = lane >> 4;
    const int r16 = lane & 15;
    const int wm = w >> 1, wn = w & 1;
    const int bm = blockIdx.y * 128, bn = blockIdx.x * 128;

    const int srow = (lane >> 2);
    const int skoff = (lane & 3) * 8;

    f32x4 acc[4][4] = {};

    for (int k0 = 0; k0 < K; k0 += 32) {
        __syncthreads();
#pragma unroll
        for (int q = 0; q < 2; ++q) {
            int arow = w * 32 + q * 16;
            gl2lds16(A + (size_t)(bm + arow + srow) * lda + k0 + skoff, As + arow * 32);
            gl2lds16(W + (size_t)(bn + arow + srow) * ldw + k0 + skoff, Bs + arow * 32);
        }
        __syncthreads();

        bf16x8 af[4], bfr[4];
#pragma unroll
        for (int i = 0; i < 4; ++i)
            af[i] = *(const bf16x8*)(As + (wm * 64 + i * 16 + r16) * 32 + quad * 8);
#pragma unroll
        for (int j = 0; j < 4; ++j)
            bfr[j] = *(const bf16x8*)(Bs + (wn * 64 + j * 16 + r16) * 32 + quad * 8);
#pragma unroll
        for (int i = 0; i < 4; ++i)
#pragma unroll
            for (int j = 0; j < 4; ++j)
                acc[i][j] = __builtin_amdgcn_mfma_f32_16x16x32_bf16(af[i], bfr[j], acc[i][j], 0, 0, 0);
    }

#pragma unroll
    for (int i = 0; i < 4; ++i) {
#pragma unroll
        for (int r = 0; r < 4; ++r) {
            int row = bm + wm * 64 + i * 16 + quad * 4 + r;
            OT* crow = C + (size_t)row * ldc;
            const float* rrow = (EPI == 3) ? (resid + (size_t)row * ldc) : nullptr;
#pragma unroll
            for (int j = 0; j < 4; ++j) {
                int col = bn + wn * 64 + j * 16 + r16;
                float v = acc[i][j][r];
                if (EPI == 1 || EPI == 2) v += bias[col];
                if (EPI == 2) v = softplusf_(v);
                if (EPI == 3) v += rrow[col];
                crow[col] = (OT)v;
            }
        }
    }
}

// ---------------- fp32 tiled GEMM (classifier): C = A * W^T, +bias ----------------
__global__ __launch_bounds__(256) void gemm_tn_bias(
    const float* __restrict__ A, int lda,
    const float* __restrict__ W, int ldw,
    float* __restrict__ C, int ldc,
    int M, int N, int K,
    const float* __restrict__ bias)
{
    __shared__ __align__(16) float As[16][68];
    __shared__ __align__(16) float Ws[16][68];
    const int t  = threadIdx.x;
    const int bm = blockIdx.y * 64, bn = blockIdx.x * 64;
    const int tx = t & 15, ty = t >> 4;
    const int lr = t >> 2;
    const int lk = (t & 3) << 2;

    float acc[4][4] = {};

    for (int k0 = 0; k0 < K; k0 += 16) {
        float4 va = {0.f, 0.f, 0.f, 0.f};
        {
            int row = bm + lr, kb = k0 + lk;
            if (row < M && kb < K) {
                const float* p = A + (size_t)row * lda + kb;
                if (kb + 3 < K) va = *(const float4*)p;
                else {
                    va.x = p[0];
                    if (kb + 1 < K) va.y = p[1];
                    if (kb + 2 < K) va.z = p[2];
                }
            }
        }
        float4 vw = {0.f, 0.f, 0.f, 0.f};
        {
            int col = bn + lr, kb = k0 + lk;
            if (col < N && kb < K) {
                const float* p = W + (size_t)col * ldw + kb;
                if (kb + 3 < K) vw = *(const float4*)p;
                else {
                    vw.x = p[0];
                    if (kb + 1 < K) vw.y = p[1];
                    if (kb + 2 < K) vw.z = p[2];
                }
            }
        }
        __syncthreads();
        As[lk + 0][lr] = va.x; As[lk + 1][lr] = va.y; As[lk + 2][lr] = va.z; As[lk + 3][lr] = va.w;
        Ws[lk + 0][lr] = vw.x; Ws[lk + 1][lr] = vw.y; Ws[lk + 2][lr] = vw.z; Ws[lk + 3][lr] = vw.w;
        __syncthreads();

#pragma unroll
        for (int kk = 0; kk < 16; ++kk) {
            float4 av = *(const float4*)&As[kk][ty << 2];
            float4 wv = *(const float4*)&Ws[kk][tx << 2];
            float a4[4] = {av.x, av.y, av.z, av.w};
            float w4[4] = {wv.x, wv.y, wv.z, wv.w};
#pragma unroll
            for (int i = 0; i < 4; ++i)
#pragma unroll
                for (int j = 0; j < 4; ++j)
                    acc[i][j] += a4[i] * w4[j];
        }
    }

#pragma unroll
    for (int i = 0; i < 4; ++i) {
        int r = bm + (ty << 2) + i;
        if (r >= M) continue;
#pragma unroll
        for (int j = 0; j < 4; ++j) {
            int c = bn + (tx << 2) + j;
            if (c >= N) continue;
            C[(size_t)r * ldc + c] = acc[i][j] + bias[c];
        }
    }
}

// ---------------- layernorm over last dim (=384), wave per row ----------------
template <typename OT>
__global__ __launch_bounds__(256) void ln_rows(
    const float* __restrict__ x, const float* __restrict__ w,
    const float* __restrict__ b, OT* __restrict__ out, int rows)
{
    int wave = threadIdx.x >> 6, lane = threadIdx.x & 63;
    int row = blockIdx.x * 4 + wave;
    if (row >= rows) return;
    const float* xr = x + (size_t)row * DMODEL;
    float v[6];
    float s = 0.f, ss = 0.f;
#pragma unroll
    for (int j = 0; j < 6; ++j) {
        v[j] = xr[lane + 64 * j];
        s += v[j];
        ss += v[j] * v[j];
    }
#pragma unroll
    for (int m = 1; m < 64; m <<= 1) {
        s  += __shfl_xor(s, m);
        ss += __shfl_xor(ss, m);
    }
    float mean = s * (1.f / DMODEL);
    float var  = ss * (1.f / DMODEL) - mean * mean;
    float rstd = rsqrtf(var + 1e-5f);
    OT* orow = out + (size_t)row * DMODEL;
#pragma unroll
    for (int j = 0; j < 6; ++j) {
        int c = lane + 64 * j;
        orow[c] = (OT)((v[j] - mean) * rstd * w[c] + b[c]);
    }
}

// ---------------- causal depthwise conv1d (K=4) + bias + SiLU ----------------
// writes fp32 (for scan) and bf16 (for xproj MFMA)
__global__ void dwconv_silu(const float* __restrict__ xz, const float* __restrict__ cw,
                            const float* __restrict__ cb, float* __restrict__ out,
                            __bf16* __restrict__ outb, int total)
{
    int idx = blockIdx.x * 256 + threadIdx.x;
    if (idx >= total) return;
    int d = idx % DINNER;
    int l = (idx / DINNER) & 255;
    int b = idx / (DINNER * 256);
    const float* src = xz + (size_t)(b * 256) * 1536 + d;
    const float* wv = cw + d * 4;
    float acc = cb[d];
#pragma unroll
    for (int k = 0; k < 4; ++k) {
        int ls = l - 3 + k;
        if (ls >= 0) acc += src[(size_t)ls * 1536] * wv[k];
    }
    float r = siluf_(acc);
    out[idx] = r;
    outb[idx] = (__bf16)r;
}

// ================= chunked selective scan =================
// proj is bf16 with row stride PROJ_LD; B at col 48+n, C at col 64+n
__global__ __launch_bounds__(256) void scan_pass1(
    const float* __restrict__ dt, const float* __restrict__ xb,
    const __bf16* __restrict__ proj, const float* __restrict__ A_log,
    float* __restrict__ S, float* __restrict__ dtsum)
{
    int d = blockIdx.x * 256 + threadIdx.x;
    int c = blockIdx.y, b = blockIdx.z;
    int tid = threadIdx.x;
    __shared__ float sB[LCH][NSTATE];
    {
        int s = tid >> 4, n = tid & 15;
        sB[s][n] = (float)proj[((size_t)(b * LSEQ + c * LCH + s)) * PROJ_LD + RLOW + n];
    }
    __syncthreads();
    float a[NSTATE], h[NSTATE];
#pragma unroll
    for (int n = 0; n < NSTATE; ++n) {
        a[n] = -__expf(A_log[(size_t)d * NSTATE + n]);
        h[n] = 0.f;
    }
    float dts = 0.f;
#pragma unroll
    for (int s = 0; s < LCH; ++s) {
        size_t off = ((size_t)(b * LSEQ + c * LCH + s)) * DINNER + d;
        float dtv = dt[off], xv = xb[off];
        dts += dtv;
        float dtx = dtv * xv;
#pragma unroll
        for (int n = 0; n < NSTATE; ++n)
            h[n] = h[n] * __expf(dtv * a[n]) + dtx * sB[s][n];
    }
    dtsum[((size_t)b * CCH + c) * DINNER + d] = dts;
#pragma unroll
    for (int n = 0; n < NSTATE; ++n)
        S[(((size_t)(b * CCH + c) * NSTATE) + n) * DINNER + d] = h[n];
}

__global__ __launch_bounds__(256) void scan_combine(
    const float* __restrict__ A_log, const float* __restrict__ dtsum,
    float* __restrict__ S)
{
    int d = blockIdx.x * 256 + threadIdx.x;
    int n = blockIdx.y, b = blockIdx.z;
    float a = -__expf(A_log[(size_t)d * NSTATE + n]);
    float h = 0.f;
#pragma unroll
    for (int c = 0; c < CCH; ++c) {
        size_t idx = (((size_t)(b * CCH + c) * NSTATE) + n) * DINNER + d;
        float loc = S[idx];
        S[idx] = h;
        h = h * __expf(a * dtsum[((size_t)b * CCH + c) * DINNER + d]) + loc;
    }
}

__global__ __launch_bounds__(256) void scan_pass2(
    const float* __restrict__ dt, const float* __restrict__ xb,
    const __bf16* __restrict__ proj, const float* __restrict__ A_log,
    const float* __restrict__ Dvec, const float* __restrict__ S,
    const float* __restrict__ xz, __bf16* __restrict__ y)
{
    int d = blockIdx.x * 256 + threadIdx.x;
    int c = blockIdx.y, b = blockIdx.z;
    int tid = threadIdx.x;
    __shared__ float sB[LCH][NSTATE], sC[LCH][NSTATE];
    {
        int s = tid >> 4, n = tid & 15;
        size_t base = ((size_t)(b * LSEQ + c * LCH + s)) * PROJ_LD;
        sB[s][n] = (float)proj[base + RLOW + n];
        sC[s][n] = (float)proj[base + RLOW + NSTATE + n];
    }
    __syncthreads();
    float a[NSTATE], h[NSTATE];
#pragma unroll
    for (int n = 0; n < NSTATE; ++n) {
        a[n] = -__expf(A_log[(size_t)d * NSTATE + n]);
        h[n] = S[(((size_t)(b * CCH + c) * NSTATE) + n) * DINNER + d];
    }
    float Dv = Dvec[d];
#pragma unroll
    for (int s = 0; s < LCH; ++s) {
        size_t row = (size_t)(b * LSEQ + c * LCH + s);
        size_t off = row * DINNER + d;
        float dtv = dt[off], xv = xb[off];
        float dtx = dtv * xv;
        float yv = 0.f;
#pragma unroll
        for (int n = 0; n < NSTATE; ++n) {
            h[n] = h[n] * __expf(dtv * a[n]) + dtx * sB[s][n];
            yv += h[n] * sC[s][n];
        }
        float z = xz[row * 1536 + DINNER + d];
        y[off] = (__bf16)((yv + xv * Dv) * siluf_(z));
    }
}

// ---------------- mean pool over L ----------------
__global__ void mean_pool(const float* __restrict__ x, float* __restrict__ out)
{
    int idx = blockIdx.x * 256 + threadIdx.x;
    if (idx >= BATCH * DMODEL) return;
    int b = idx / DMODEL, m = idx % DMODEL;
    const float* p = x + (size_t)(b * LSEQ) * DMODEL + m;
    float s = 0.f;
    for (int l = 0; l < LSEQ; ++l) s += p[(size_t)l * DMODEL];
    out[idx] = s * (1.f / LSEQ);
}

// ---------------- host launch ----------------
static inline int ceil_div(int a, int b) { return (a + b - 1) / b; }

extern "C" void kernel_launch(void* const* d_in, const int* in_sizes, int n_in,
                              void* d_out, int out_size, void* d_ws, size_t ws_size,
                              hipStream_t stream)
{
    const float* x        = (const float*)d_in[0];
    const float* patch_w  = (const float*)d_in[1];
    const float* patch_b  = (const float*)d_in[2];
    const float* norm_w   = (const float*)d_in[3];
    const float* norm_b   = (const float*)d_in[4];
    const float* in_proj  = (const float*)d_in[5];
    const float* conv_w   = (const float*)d_in[6];
    const float* conv_b   = (const float*)d_in[7];
    const float* A_log    = (const float*)d_in[8];
    const float* D_ssm    = (const float*)d_in[9];
    const float* xproj_w  = (const float*)d_in[10];
    const float* dtproj_w = (const float*)d_in[11];
    const float* dtproj_b = (const float*)d_in[12];
    const float* out_proj = (const float*)d_in[13];
    const float* fnorm_w  = (const float*)d_in[14];
    const float* fnorm_b  = (const float*)d_in[15];
    const float* cls_w    = (const float*)d_in[16];
    const float* cls_b    = (const float*)d_in[17];
    float* out = (float*)d_out;

    float* ws = (float*)d_ws;
    // float-unit offsets
    const size_t OFF_XZ   = 0;
    const size_t OFF_T    = OFF_XZ + (size_t)NROWS * 1536;
    const size_t OFF_XB   = OFF_T  + (size_t)NROWS * DMODEL;
    const size_t OFF_DT   = OFF_XB + (size_t)NROWS * DINNER;
    const size_t OFF_S    = OFF_DT + (size_t)NROWS * DINNER;
    const size_t OFF_DSUM = OFF_S  + (size_t)BATCH * CCH * NSTATE * DINNER;
    const size_t OFF_POOL = OFF_DSUM + (size_t)BATCH * CCH * DINNER;
    // bf16 region (sizes in float units = elems/2)
    const size_t OFF_XNBF = OFF_POOL + (size_t)BATCH * DMODEL;
    const size_t OFF_YBF  = OFF_XNBF + (size_t)NROWS * DMODEL / 2;
    const size_t OFF_XBBF = OFF_YBF  + (size_t)NROWS * DINNER / 2;
    const size_t OFF_PRBF = OFF_XBBF + (size_t)NROWS * DINNER / 2;
    const size_t OFF_WIP  = OFF_PRBF + (size_t)NROWS * PROJ_LD / 2;
    const size_t OFF_WOP  = OFF_WIP + (size_t)NLAYER * 2 * DINNER * DMODEL / 2;
    const size_t OFF_WP   = OFF_WOP + (size_t)NLAYER * DMODEL * DINNER / 2;
    const size_t OFF_WXP  = OFF_WP  + (size_t)DMODEL * KPATCH_PAD / 2;
    const size_t OFF_WDT  = OFF_WXP + (size_t)NLAYER * PROJ_LD * DINNER / 2;

    float*  xz     = ws + OFF_XZ;
    float*  t      = ws + OFF_T;
    float*  xb     = ws + OFF_XB;
    float*  dtbuf  = ws + OFF_DT;
    float*  Sbuf   = ws + OFF_S;
    float*  dsum   = ws + OFF_DSUM;
    float*  pooled = ws + OFF_POOL;
    __bf16* xnbf   = (__bf16*)(ws + OFF_XNBF);
    __bf16* ybf    = (__bf16*)(ws + OFF_YBF);
    __bf16* xbbf   = (__bf16*)(ws + OFF_XBBF);
    __bf16* projbf = (__bf16*)(ws + OFF_PRBF);
    __bf16* wip    = (__bf16*)(ws + OFF_WIP);
    __bf16* wop    = (__bf16*)(ws + OFF_WOP);
    __bf16* wpp    = (__bf16*)(ws + OFF_WP);
    __bf16* wxp    = (__bf16*)(ws + OFF_WXP);
    __bf16* wdt    = (__bf16*)(ws + OFF_WDT);
    __bf16* colbf  = ybf;   // im2col aliases ybf+xbbf (disjoint liveness; 640 <= 768*2... fits in ybf(768)+0)

    // 0. weight conversions (fp32 -> bf16, padded where needed)
    {
        int nip = NLAYER * 2 * DINNER * DMODEL;
        f2b<<<ceil_div(nip, 256), 256, 0, stream>>>(in_proj, wip, nip);
        int nop = NLAYER * DMODEL * DINNER;
        f2b<<<ceil_div(nop, 256), 256, 0, stream>>>(out_proj, wop, nop);
        padw_patch<<<ceil_div(DMODEL * KPATCH_PAD, 256), 256, 0, stream>>>(patch_w, wpp);
        padw_xp<<<ceil_div(NLAYER * PROJ_LD * DINNER, 256), 256, 0, stream>>>(xproj_w, wxp);
        padw_dt<<<ceil_div(NLAYER * DINNER * KDT_PAD, 256), 256, 0, stream>>>(dtproj_w, wdt);
    }

    // 1. im2col + patch-embed MFMA GEMM -> t (8192,384)
    {
        im2col_bf<<<ceil_div(NROWS * KPATCH_PAD, 256), 256, 0, stream>>>(x, colbf);
        dim3 g(DMODEL / 128, NROWS / 128);
        mfma_gemm<1, float><<<g, 256, 0, stream>>>(colbf, KPATCH_PAD, wpp, KPATCH_PAD,
                                                   t, DMODEL, KPATCH_PAD, patch_b, nullptr);
    }

    // 2. mamba blocks
    for (int l = 0; l < NLAYER; ++l) {
        const float* nw   = norm_w   + (size_t)l * DMODEL;
        const float* nb   = norm_b   + (size_t)l * DMODEL;
        const __bf16* ipw = wip + (size_t)l * 2 * DINNER * DMODEL;
        const float* cw   = conv_w   + (size_t)l * DINNER * KCONV;
        const float* cb   = conv_b   + (size_t)l * DINNER;
        const float* al   = A_log    + (size_t)l * DINNER * NSTATE;
        const float* dp   = D_ssm    + (size_t)l * DINNER;
        const __bf16* xw  = wxp + (size_t)l * PROJ_LD * DINNER;
        const __bf16* dtw = wdt + (size_t)l * DINNER * KDT_PAD;
        const float* dtb  = dtproj_b + (size_t)l * DINNER;
        const __bf16* opw = wop + (size_t)l * DMODEL * DINNER;

        // LN -> bf16
        ln_rows<__bf16><<<NROWS / 4, 256, 0, stream>>>(t, nw, nb, xnbf, NROWS);
        // in_proj (MFMA): (8192,384)bf16 @ (1536,384)^T -> xz fp32
        {
            dim3 g(2 * DINNER / 128, NROWS / 128);
            mfma_gemm<0, float><<<g, 256, 0, stream>>>(xnbf, DMODEL, ipw, DMODEL,
                                                       xz, 2 * DINNER, DMODEL, nullptr, nullptr);
        }
        // causal depthwise conv + silu -> xb (fp32) + xbbf (bf16)
        {
            int total = NROWS * DINNER;
            dwconv_silu<<<ceil_div(total, 256), 256, 0, stream>>>(xz, cw, cb, xb, xbbf, total);
        }
        // xproj (MFMA): (8192,768)bf16 @ (128,768)^T -> projbf bf16 (ld 128)
        {
            dim3 g(PROJ_LD / 128, NROWS / 128);
            mfma_gemm<0, __bf16><<<g, 256, 0, stream>>>(xbbf, DINNER, xw, DINNER,
                                                        projbf, PROJ_LD, DINNER, nullptr, nullptr);
        }
        // dtproj (MFMA) + softplus: (8192,64)bf16 @ (768,64)^T -> dtbuf fp32
        {
            dim3 g(DINNER / 128, NROWS / 128);
            mfma_gemm<2, float><<<g, 256, 0, stream>>>(projbf, PROJ_LD, dtw, KDT_PAD,
                                                       dtbuf, DINNER, KDT_PAD, dtb, nullptr);
        }
        // chunked scan; gated bf16 y -> ybf
        {
            dim3 g1(DINNER / 256, CCH, BATCH);
            scan_pass1<<<g1, 256, 0, stream>>>(dtbuf, xb, projbf, al, Sbuf, dsum);
            dim3 g2(DINNER / 256, NSTATE, BATCH);
            scan_combine<<<g2, 256, 0, stream>>>(al, dsum, Sbuf);
            scan_pass2<<<g1, 256, 0, stream>>>(dtbuf, xb, projbf, al, dp, Sbuf, xz, ybf);
        }
        // out_proj (MFMA) + residual: (8192,768)bf16 @ (384,768)^T + t -> t
        {
            dim3 g(DMODEL / 128, NROWS / 128);
            mfma_gemm<3, float><<<g, 256, 0, stream>>>(ybf, DINNER, opw, DINNER,
                                                       t, DMODEL, DINNER, nullptr, t);
        }
    }

    // 3. final LN -> mean pool -> classifier (fp32)
    ln_rows<float><<<NROWS / 4, 256, 0, stream>>>(t, fnorm_w, fnorm_b, dtbuf, NROWS);
    mean_pool<<<ceil_div(BATCH * DMODEL, 256), 256, 0, stream>>>(dtbuf, pooled);
    {
        dim3 g(ceil_div(NCLS, 64), ceil_div(BATCH, 64));
        gemm_tn_bias<<<g, 256, 0, stream>>>(pooled, DMODEL, cls_w, DMODEL, out, NCLS,
                                            BATCH, NCLS, DMODEL, cls_b);
    }
}

// Round 5
// 904.871 us; speedup vs baseline: 2.9400x; 1.0373x over previous
//
#include <hip/hip_runtime.h>
#include <cstdint>
#include <cstddef>

// ---------------- constants ----------------
#define BATCH 32
#define LSEQ  256
#define DMODEL 384
#define DINNER 768
#define NSTATE 16
#define RLOW   48
#define KCONV  4
#define NCLS   1000
#define NLAYER 4
#define KPATCH 588    // 3*14*14
#define KPATCH_PAD 640
#define NROWS  (BATCH*LSEQ)   // 8192
#define CCH 16
#define LCH 16
#define PROJ_LD 128   // padded xproj output width (80 -> 128)
#define KDT_PAD 64    // padded dtproj K (48 -> 64)

typedef __bf16 bf16x8 __attribute__((ext_vector_type(8)));
typedef float  f32x4  __attribute__((ext_vector_type(4)));

__device__ __forceinline__ float siluf_(float x)    { return x / (1.f + __expf(-x)); }
__device__ __forceinline__ float softplusf_(float x){ return fmaxf(x, 0.f) + log1pf(__expf(-fabsf(x))); }

__device__ __forceinline__ void gl2lds16(const void* g, void* l) {
    __builtin_amdgcn_global_load_lds(
        (const __attribute__((address_space(1))) unsigned*)g,
        (__attribute__((address_space(3))) unsigned*)l, 16, 0, 0);
}

// ---------------- fused weight prep ----------------
#define NW0 (NLAYER*2*DINNER*DMODEL)
#define NW1 (NLAYER*DMODEL*DINNER)
#define NW2 (DMODEL*KPATCH_PAD)
#define NW3 (NLAYER*PROJ_LD*DINNER)
#define NW4 (NLAYER*DINNER*KDT_PAD)
#define NWTOT (NW0+NW1+NW2+NW3+NW4)

__global__ void prep_weights(const float* __restrict__ in_proj, const float* __restrict__ out_proj,
                             const float* __restrict__ patch_w, const float* __restrict__ xproj_w,
                             const float* __restrict__ dtproj_w,
                             __bf16* __restrict__ wip, __bf16* __restrict__ wop,
                             __bf16* __restrict__ wpp, __bf16* __restrict__ wxp,
                             __bf16* __restrict__ wdt)
{
    int i = blockIdx.x * 256 + threadIdx.x;
    if (i < NW0) { wip[i] = (__bf16)in_proj[i]; return; }
    i -= NW0;
    if (i < NW1) { wop[i] = (__bf16)out_proj[i]; return; }
    i -= NW1;
    if (i < NW2) {
        int k = i % KPATCH_PAD, r = i / KPATCH_PAD;
        wpp[i] = (k < KPATCH) ? (__bf16)patch_w[r * KPATCH + k] : (__bf16)0.f;
        return;
    }
    i -= NW2;
    if (i < NW3) {
        int c = i % DINNER;
        int r = (i / DINNER) % PROJ_LD;
        int l = i / (DINNER * PROJ_LD);
        wxp[i] = (r < 80) ? (__bf16)xproj_w[((size_t)l * 80 + r) * DINNER + c] : (__bf16)0.f;
        return;
    }
    i -= NW3;
    if (i < NW4) {
        int k = i % KDT_PAD;
        int r = (i / KDT_PAD) % DINNER;
        int l = i / (KDT_PAD * DINNER);
        wdt[i] = (k < RLOW) ? (__bf16)dtproj_w[((size_t)l * DINNER + r) * RLOW + k] : (__bf16)0.f;
    }
}

// ---------------- im2col (bf16, K padded to 640) ----------------
__global__ void im2col_bf(const float* __restrict__ x, __bf16* __restrict__ col) {
    int idx = blockIdx.x * 256 + threadIdx.x;
    if (idx >= NROWS * KPATCH_PAD) return;
    int k = idx % KPATCH_PAD;
    int row = idx / KPATCH_PAD;
    if (k >= KPATCH) { col[idx] = (__bf16)0.f; return; }
    int b = row >> 8, l = row & 255;
    int py = l >> 4, px = l & 15;
    int c = k / 196;
    int rem = k % 196;
    int i = rem / 14, j = rem % 14;
    col[idx] = (__bf16)x[(((size_t)(b * 3 + c) * 224) + py * 14 + i) * 224 + px * 14 + j];
}

// ---------------- bf16 MFMA GEMM ----------------
// EPI: 0 none, 1 +bias, 2 softplus(+bias), 3 +resid(f32), 4 in_proj split (bf16, silu on cols>=DINNER)
template <int EPI, typename OT>
__global__ __launch_bounds__(256) void mfma_gemm(
    const __bf16* __restrict__ A, int lda,
    const __bf16* __restrict__ W, int ldw,
    OT* __restrict__ C, int ldc,
    int K,
    const float* __restrict__ bias,
    const float* __restrict__ resid)
{
    __shared__ __bf16 As[128 * 32];
    __shared__ __bf16 Bs[128 * 32];
    const int t = threadIdx.x;
    const int w = t >> 6;
    const int lane = t & 63;
    const int quad = lane >> 4;
    const int r16 = lane & 15;
    const int wm = w >> 1, wn = w & 1;
    const int bm = blockIdx.y * 128, bn = blockIdx.x * 128;

    const int srow = (lane >> 2);
    const int skoff = (lane & 3) * 8;

    f32x4 acc[4][4] = {};

    for (int k0 = 0; k0 < K; k0 += 32) {
        __syncthreads();
#pragma unroll
        for (int q = 0; q < 2; ++q) {
            int arow = w * 32 + q * 16;
            gl2lds16(A + (size_t)(bm + arow + srow) * lda + k0 + skoff, As + arow * 32);
            gl2lds16(W + (size_t)(bn + arow + srow) * ldw + k0 + skoff, Bs + arow * 32);
        }
        __syncthreads();

        bf16x8 af[4], bfr[4];
#pragma unroll
        for (int i = 0; i < 4; ++i)
            af[i] = *(const bf16x8*)(As + (wm * 64 + i * 16 + r16) * 32 + quad * 8);
#pragma unroll
        for (int j = 0; j < 4; ++j)
            bfr[j] = *(const bf16x8*)(Bs + (wn * 64 + j * 16 + r16) * 32 + quad * 8);
#pragma unroll
        for (int i = 0; i < 4; ++i)
#pragma unroll
            for (int j = 0; j < 4; ++j)
                acc[i][j] = __builtin_amdgcn_mfma_f32_16x16x32_bf16(af[i], bfr[j], acc[i][j], 0, 0, 0);
    }

    const bool zhalf = (EPI == 4) && (bn >= DINNER);
#pragma unroll
    for (int i = 0; i < 4; ++i) {
#pragma unroll
        for (int r = 0; r < 4; ++r) {
            int row = bm + wm * 64 + i * 16 + quad * 4 + r;
            OT* crow = C + (size_t)row * ldc;
            const float* rrow = (EPI == 3) ? (resid + (size_t)row * ldc) : nullptr;
#pragma unroll
            for (int j = 0; j < 4; ++j) {
                int col = bn + wn * 64 + j * 16 + r16;
                float v = acc[i][j][r];
                if (EPI == 1 || EPI == 2) v += bias[col];
                if (EPI == 2) v = softplusf_(v);
                if (EPI == 3) v += rrow[col];
                if (EPI == 4 && zhalf) v = siluf_(v);
                crow[col] = (OT)v;
            }
        }
    }
}

// ---------------- layernorm (384), wave per row ----------------
template <typename OT>
__global__ __launch_bounds__(256) void ln_rows(
    const float* __restrict__ x, const float* __restrict__ w,
    const float* __restrict__ b, OT* __restrict__ out, int rows)
{
    int wave = threadIdx.x >> 6, lane = threadIdx.x & 63;
    int row = blockIdx.x * 4 + wave;
    if (row >= rows) return;
    const float* xr = x + (size_t)row * DMODEL;
    float v[6];
    float s = 0.f, ss = 0.f;
#pragma unroll
    for (int j = 0; j < 6; ++j) {
        v[j] = xr[lane + 64 * j];
        s += v[j];
        ss += v[j] * v[j];
    }
#pragma unroll
    for (int m = 1; m < 64; m <<= 1) {
        s  += __shfl_xor(s, m);
        ss += __shfl_xor(ss, m);
    }
    float mean = s * (1.f / DMODEL);
    float var  = ss * (1.f / DMODEL) - mean * mean;
    float rstd = rsqrtf(var + 1e-5f);
    OT* orow = out + (size_t)row * DMODEL;
#pragma unroll
    for (int j = 0; j < 6; ++j) {
        int c = lane + 64 * j;
        orow[c] = (OT)((v[j] - mean) * rstd * w[c] + b[c]);
    }
}

// ---------------- causal depthwise conv1d + bias + SiLU (bf16 in/out) ----------------
__global__ void dwconv_silu(const __bf16* __restrict__ xz, const float* __restrict__ cw,
                            const float* __restrict__ cb, __bf16* __restrict__ outb, int total)
{
    int idx = blockIdx.x * 256 + threadIdx.x;
    if (idx >= total) return;
    int d = idx % DINNER;
    int l = (idx / DINNER) & 255;
    int b = idx / (DINNER * 256);
    const __bf16* src = xz + (size_t)(b * 256) * 1536 + d;
    const float* wv = cw + d * 4;
    float acc = cb[d];
#pragma unroll
    for (int k = 0; k < 4; ++k) {
        int ls = l - 3 + k;
        if (ls >= 0) acc += (float)src[(size_t)ls * 1536] * wv[k];
    }
    outb[idx] = (__bf16)siluf_(acc);
}

// ================= chunked selective scan =================
__global__ __launch_bounds__(256) void scan_pass1(
    const float* __restrict__ dt, const __bf16* __restrict__ xb,
    const __bf16* __restrict__ proj, const float* __restrict__ A_log,
    float* __restrict__ S, float* __restrict__ dtsum)
{
    int d = blockIdx.x * 256 + threadIdx.x;
    int c = blockIdx.y, b = blockIdx.z;
    int tid = threadIdx.x;
    __shared__ float sB[LCH][NSTATE];
    {
        int s = tid >> 4, n = tid & 15;
        sB[s][n] = (float)proj[((size_t)(b * LSEQ + c * LCH + s)) * PROJ_LD + RLOW + n];
    }
    __syncthreads();
    float a[NSTATE], h[NSTATE];
#pragma unroll
    for (int n = 0; n < NSTATE; ++n) {
        a[n] = -__expf(A_log[(size_t)d * NSTATE + n]);
        h[n] = 0.f;
    }
    float dts = 0.f;
#pragma unroll
    for (int s = 0; s < LCH; ++s) {
        size_t off = ((size_t)(b * LSEQ + c * LCH + s)) * DINNER + d;
        float dtv = dt[off], xv = (float)xb[off];
        dts += dtv;
        float dtx = dtv * xv;
#pragma unroll
        for (int n = 0; n < NSTATE; ++n)
            h[n] = h[n] * __expf(dtv * a[n]) + dtx * sB[s][n];
    }
    dtsum[((size_t)b * CCH + c) * DINNER + d] = dts;
#pragma unroll
    for (int n = 0; n < NSTATE; ++n)
        S[(((size_t)(b * CCH + c) * NSTATE) + n) * DINNER + d] = h[n];
}

__global__ __launch_bounds__(256) void scan_combine(
    const float* __restrict__ A_log, const float* __restrict__ dtsum,
    float* __restrict__ S)
{
    int d = blockIdx.x * 256 + threadIdx.x;
    int n = blockIdx.y, b = blockIdx.z;
    float a = -__expf(A_log[(size_t)d * NSTATE + n]);
    float h = 0.f;
#pragma unroll
    for (int c = 0; c < CCH; ++c) {
        size_t idx = (((size_t)(b * CCH + c) * NSTATE) + n) * DINNER + d;
        float loc = S[idx];
        S[idx] = h;
        h = h * __expf(a * dtsum[((size_t)b * CCH + c) * DINNER + d]) + loc;
    }
}

__global__ __launch_bounds__(256) void scan_pass2(
    const float* __restrict__ dt, const __bf16* __restrict__ xb,
    const __bf16* __restrict__ proj, const float* __restrict__ A_log,
    const float* __restrict__ Dvec, const float* __restrict__ S,
    const __bf16* __restrict__ xz, __bf16* __restrict__ y)
{
    int d = blockIdx.x * 256 + threadIdx.x;
    int c = blockIdx.y, b = blockIdx.z;
    int tid = threadIdx.x;
    __shared__ float sB[LCH][NSTATE], sC[LCH][NSTATE];
    {
        int s = tid >> 4, n = tid & 15;
        size_t base = ((size_t)(b * LSEQ + c * LCH + s)) * PROJ_LD;
        sB[s][n] = (float)proj[base + RLOW + n];
        sC[s][n] = (float)proj[base + RLOW + NSTATE + n];
    }
    __syncthreads();
    float a[NSTATE], h[NSTATE];
#pragma unroll
    for (int n = 0; n < NSTATE; ++n) {
        a[n] = -__expf(A_log[(size_t)d * NSTATE + n]);
        h[n] = S[(((size_t)(b * CCH + c) * NSTATE) + n) * DINNER + d];
    }
    float Dv = Dvec[d];
#pragma unroll
    for (int s = 0; s < LCH; ++s) {
        size_t row = (size_t)(b * LSEQ + c * LCH + s);
        size_t off = row * DINNER + d;
        float dtv = dt[off], xv = (float)xb[off];
        float dtx = dtv * xv;
        float yv = 0.f;
#pragma unroll
        for (int n = 0; n < NSTATE; ++n) {
            h[n] = h[n] * __expf(dtv * a[n]) + dtx * sB[s][n];
            yv += h[n] * sC[s][n];
        }
        float g = (float)xz[row * 1536 + DINNER + d];
        y[off] = (__bf16)((yv + xv * Dv) * g);
    }
}

// ---------------- mean pool ----------------
__global__ void mean_pool(const float* __restrict__ x, float* __restrict__ out)
{
    int idx = blockIdx.x * 256 + threadIdx.x;
    if (idx >= BATCH * DMODEL) return;
    int b = idx / DMODEL, m = idx % DMODEL;
    const float* p = x + (size_t)(b * LSEQ) * DMODEL + m;
    float s = 0.f;
    for (int l = 0; l < LSEQ; ++l) s += p[(size_t)l * DMODEL];
    out[idx] = s * (1.f / LSEQ);
}

// ---------------- classifier GEMV: wave per output ----------------
__global__ __launch_bounds__(256) void cls_gemv(
    const float* __restrict__ pooled, const float* __restrict__ W,
    const float* __restrict__ bias, float* __restrict__ out)
{
    int wave = threadIdx.x >> 6, lane = threadIdx.x & 63;
    int c = blockIdx.x * 4 + wave;
    int b = blockIdx.y;
    if (c >= NCLS) return;
    const float* pr = pooled + (size_t)b * DMODEL;
    const float* wr = W + (size_t)c * DMODEL;
    float s = 0.f;
#pragma unroll
    for (int j = 0; j < 6; ++j) {
        int k = lane + 64 * j;
        s += pr[k] * wr[k];
    }
#pragma unroll
    for (int m = 1; m < 64; m <<= 1) s += __shfl_xor(s, m);
    if (lane == 0) out[(size_t)b * NCLS + c] = s + bias[c];
}

// ---------------- host launch ----------------
static inline int ceil_div(int a, int b) { return (a + b - 1) / b; }

extern "C" void kernel_launch(void* const* d_in, const int* in_sizes, int n_in,
                              void* d_out, int out_size, void* d_ws, size_t ws_size,
                              hipStream_t stream)
{
    const float* x        = (const float*)d_in[0];
    const float* patch_w  = (const float*)d_in[1];
    const float* patch_b  = (const float*)d_in[2];
    const float* norm_w   = (const float*)d_in[3];
    const float* norm_b   = (const float*)d_in[4];
    const float* in_proj  = (const float*)d_in[5];
    const float* conv_w   = (const float*)d_in[6];
    const float* conv_b   = (const float*)d_in[7];
    const float* A_log    = (const float*)d_in[8];
    const float* D_ssm    = (const float*)d_in[9];
    const float* xproj_w  = (const float*)d_in[10];
    const float* dtproj_w = (const float*)d_in[11];
    const float* dtproj_b = (const float*)d_in[12];
    const float* out_proj = (const float*)d_in[13];
    const float* fnorm_w  = (const float*)d_in[14];
    const float* fnorm_b  = (const float*)d_in[15];
    const float* cls_w    = (const float*)d_in[16];
    const float* cls_b    = (const float*)d_in[17];
    float* out = (float*)d_out;

    float* ws = (float*)d_ws;
    const size_t OFF_T    = 0;
    const size_t OFF_DT   = OFF_T  + (size_t)NROWS * DMODEL;
    const size_t OFF_S    = OFF_DT + (size_t)NROWS * DINNER;
    const size_t OFF_DSUM = OFF_S  + (size_t)BATCH * CCH * NSTATE * DINNER;
    const size_t OFF_POOL = OFF_DSUM + (size_t)BATCH * CCH * DINNER;
    const size_t OFF_XZBF = OFF_POOL + (size_t)BATCH * DMODEL;
    const size_t OFF_XNBF = OFF_XZBF + (size_t)NROWS * 1536 / 2;
    const size_t OFF_YBF  = OFF_XNBF + (size_t)NROWS * DMODEL / 2;
    const size_t OFF_XBBF = OFF_YBF  + (size_t)NROWS * DINNER / 2;
    const size_t OFF_PRBF = OFF_XBBF + (size_t)NROWS * DINNER / 2;
    const size_t OFF_WIP  = OFF_PRBF + (size_t)NROWS * PROJ_LD / 2;
    const size_t OFF_WOP  = OFF_WIP + (size_t)NW0 / 2;
    const size_t OFF_WPP  = OFF_WOP + (size_t)NW1 / 2;
    const size_t OFF_WXP  = OFF_WPP + (size_t)NW2 / 2;
    const size_t OFF_WDT  = OFF_WXP + (size_t)NW3 / 2;

    float*  t      = ws + OFF_T;
    float*  dtbuf  = ws + OFF_DT;
    float*  Sbuf   = ws + OFF_S;
    float*  dsum   = ws + OFF_DSUM;
    float*  pooled = ws + OFF_POOL;
    __bf16* xzbf   = (__bf16*)(ws + OFF_XZBF);
    __bf16* xnbf   = (__bf16*)(ws + OFF_XNBF);
    __bf16* ybf    = (__bf16*)(ws + OFF_YBF);
    __bf16* xbbf   = (__bf16*)(ws + OFF_XBBF);
    __bf16* projbf = (__bf16*)(ws + OFF_PRBF);
    __bf16* wip    = (__bf16*)(ws + OFF_WIP);
    __bf16* wop    = (__bf16*)(ws + OFF_WOP);
    __bf16* wpp    = (__bf16*)(ws + OFF_WPP);
    __bf16* wxp    = (__bf16*)(ws + OFF_WXP);
    __bf16* wdt    = (__bf16*)(ws + OFF_WDT);
    __bf16* colbf  = ybf;   // im2col aliases ybf (disjoint liveness)

    // 0. fused weight conversion
    prep_weights<<<ceil_div(NWTOT, 256), 256, 0, stream>>>(
        in_proj, out_proj, patch_w, xproj_w, dtproj_w, wip, wop, wpp, wxp, wdt);

    // 1. im2col + patch-embed MFMA GEMM -> t (8192,384)
    {
        im2col_bf<<<ceil_div(NROWS * KPATCH_PAD, 256), 256, 0, stream>>>(x, colbf);
        dim3 g(DMODEL / 128, NROWS / 128);
        mfma_gemm<1, float><<<g, 256, 0, stream>>>(colbf, KPATCH_PAD, wpp, KPATCH_PAD,
                                                   t, DMODEL, KPATCH_PAD, patch_b, nullptr);
    }

    // 2. mamba blocks
    for (int l = 0; l < NLAYER; ++l) {
        const float* nw   = norm_w   + (size_t)l * DMODEL;
        const float* nb   = norm_b   + (size_t)l * DMODEL;
        const __bf16* ipw = wip + (size_t)l * 2 * DINNER * DMODEL;
        const float* cw   = conv_w   + (size_t)l * DINNER * KCONV;
        const float* cb   = conv_b   + (size_t)l * DINNER;
        const float* al   = A_log    + (size_t)l * DINNER * NSTATE;
        const float* dp   = D_ssm    + (size_t)l * DINNER;
        const __bf16* xw  = wxp + (size_t)l * PROJ_LD * DINNER;
        const __bf16* dtw = wdt + (size_t)l * DINNER * KDT_PAD;
        const float* dtb  = dtproj_b + (size_t)l * DINNER;
        const __bf16* opw = wop + (size_t)l * DMODEL * DINNER;

        ln_rows<__bf16><<<NROWS / 4, 256, 0, stream>>>(t, nw, nb, xnbf, NROWS);
        {
            dim3 g(2 * DINNER / 128, NROWS / 128);
            mfma_gemm<4, __bf16><<<g, 256, 0, stream>>>(xnbf, DMODEL, ipw, DMODEL,
                                                        xzbf, 1536, DMODEL, nullptr, nullptr);
        }
        {
            int total = NROWS * DINNER;
            dwconv_silu<<<ceil_div(total, 256), 256, 0, stream>>>(xzbf, cw, cb, xbbf, total);
        }
        {
            dim3 g(PROJ_LD / 128, NROWS / 128);
            mfma_gemm<0, __bf16><<<g, 256, 0, stream>>>(xbbf, DINNER, xw, DINNER,
                                                        projbf, PROJ_LD, DINNER, nullptr, nullptr);
        }
        {
            dim3 g(DINNER / 128, NROWS / 128);
            mfma_gemm<2, float><<<g, 256, 0, stream>>>(projbf, PROJ_LD, dtw, KDT_PAD,
                                                       dtbuf, DINNER, KDT_PAD, dtb, nullptr);
        }
        {
            dim3 g1(DINNER / 256, CCH, BATCH);
            scan_pass1<<<g1, 256, 0, stream>>>(dtbuf, xbbf, projbf, al, Sbuf, dsum);
            dim3 g2(DINNER / 256, NSTATE, BATCH);
            scan_combine<<<g2, 256, 0, stream>>>(al, dsum, Sbuf);
            scan_pass2<<<g1, 256, 0, stream>>>(dtbuf, xbbf, projbf, al, dp, Sbuf, xzbf, ybf);
        }
        {
            dim3 g(DMODEL / 128, NROWS / 128);
            mfma_gemm<3, float><<<g, 256, 0, stream>>>(ybf, DINNER, opw, DINNER,
                                                       t, DMODEL, DINNER, nullptr, t);
        }
    }

    // 3. final LN -> mean pool -> classifier
    ln_rows<float><<<NROWS / 4, 256, 0, stream>>>(t, fnorm_w, fnorm_b, dtbuf, NROWS);
    mean_pool<<<ceil_div(BATCH * DMODEL, 256), 256, 0, stream>>>(dtbuf, pooled);
    {
        dim3 g(ceil_div(NCLS, 4), BATCH);
        cls_gemv<<<g, 256, 0, stream>>>(pooled, cls_w, cls_b, out);
    }
}